// Round 2
// baseline (827.333 us; speedup 1.0000x reference)
//
#include <hip/hip_runtime.h>

#define N_NODES 100000
#define N_EDGES 1250000
#define F_IN    128
#define H_DIM   64
#define N_CLS   10
#define N_GRAPH 1000

// ---------------- CSR build ----------------

__global__ void count_deg(const int* __restrict__ ei, int* __restrict__ deg) {
    int e = blockIdx.x * blockDim.x + threadIdx.x;
    if (e < N_EDGES) {
        int dst = ei[N_EDGES + e];
        atomicAdd(&deg[dst], 1);
    }
}

__global__ void compute_dinv(const int* __restrict__ deg, float* __restrict__ dinv) {
    int i = blockIdx.x * blockDim.x + threadIdx.x;
    if (i < N_NODES) dinv[i] = rsqrtf((float)deg[i] + 1.0f);  // +1 self-loop
}

// single-block scan over N_NODES (exclusive prefix -> rowptr, rowptr[N]=E)
__global__ void scan_deg(const int* __restrict__ deg, int* __restrict__ rowptr) {
    const int T = 1024;
    int tid = threadIdx.x;
    int chunk = (N_NODES + T - 1) / T;
    int beg = tid * chunk;
    int end = beg + chunk;
    if (beg > N_NODES) beg = N_NODES;
    if (end > N_NODES) end = N_NODES;
    int s = 0;
    for (int i = beg; i < end; ++i) s += deg[i];
    __shared__ int sums[T];
    sums[tid] = s;
    __syncthreads();
    for (int off = 1; off < T; off <<= 1) {
        int v = (tid >= off) ? sums[tid - off] : 0;
        __syncthreads();
        sums[tid] += v;
        __syncthreads();
    }
    int run = sums[tid] - s;  // exclusive prefix of this chunk
    for (int i = beg; i < end; ++i) { rowptr[i] = run; run += deg[i]; }
    if (tid == T - 1) rowptr[N_NODES] = sums[T - 1];
}

__global__ void fill_csr(const int* __restrict__ ei, const int* __restrict__ rowptr,
                         int* __restrict__ cur, int* __restrict__ colsrc) {
    int e = blockIdx.x * blockDim.x + threadIdx.x;
    if (e < N_EDGES) {
        int src = ei[e];
        int dst = ei[N_EDGES + e];
        int pos = rowptr[dst] + atomicAdd(&cur[dst], 1);
        colsrc[pos] = src;
    }
}

// ---------------- dense compute ----------------

// Y[N,64] = X[N,K] @ W[K,64]; block = 256 threads = 4 rows x 64 cols
__global__ void gemm_xw(const float* __restrict__ X, const float* __restrict__ W,
                        float* __restrict__ Y, int K) {
    __shared__ float xs[4][F_IN];
    int tid  = threadIdx.x;
    int rg   = tid >> 6;
    int lane = tid & 63;
    int row  = blockIdx.x * 4 + rg;
    if (row < N_NODES) {
        xs[rg][lane] = X[(size_t)row * K + lane];
        if (K > 64) xs[rg][lane + 64] = X[(size_t)row * K + lane + 64];
    }
    __syncthreads();
    float acc = 0.f;
    for (int k = 0; k < K; ++k)
        acc += xs[rg][k] * W[k * H_DIM + lane];
    if (row < N_NODES) Y[(size_t)row * H_DIM + lane] = acc;
}

// out[i] = [relu](sum_{e: dst=i} h[src]*dinv[src]*dinv[i] + h[i]*dinv[i]^2 + b)
__global__ void agg_norm(const float* __restrict__ Hin, const float* __restrict__ dinv,
                         const int* __restrict__ rowptr, const int* __restrict__ colsrc,
                         const float* __restrict__ bias, float* __restrict__ Hout,
                         int do_relu) {
    int tid  = threadIdx.x;
    int node = blockIdx.x * 4 + (tid >> 6);
    int lane = tid & 63;
    if (node >= N_NODES) return;
    float di  = dinv[node];
    float acc = Hin[(size_t)node * H_DIM + lane] * di * di;
    int beg = rowptr[node], end = rowptr[node + 1];
    for (int p = beg; p < end; ++p) {
        int s = colsrc[p];
        acc += Hin[(size_t)s * H_DIM + lane] * (dinv[s] * di);
    }
    acc += bias[lane];
    if (do_relu) acc = fmaxf(acc, 0.f);
    Hout[(size_t)node * H_DIM + lane] = acc;
}

// ---------------- pooling + head ----------------

__global__ void pool_nodes(const float* __restrict__ Hin, const int* __restrict__ batch,
                           float* __restrict__ pooled, float* __restrict__ cnt) {
    int tid  = threadIdx.x;
    int node = blockIdx.x * 4 + (tid >> 6);
    int lane = tid & 63;
    if (node >= N_NODES) return;
    int g = batch[node];
    atomicAdd(&pooled[g * H_DIM + lane], Hin[(size_t)node * H_DIM + lane]);
    if (lane == 0) atomicAdd(&cnt[g], 1.0f);
}

__global__ void head_kernel(const float* __restrict__ pooled, const float* __restrict__ cnt,
                            const float* __restrict__ Wl, const float* __restrict__ bl,
                            float* __restrict__ out) {
    int g    = blockIdx.x;
    int lane = threadIdx.x;  // 0..63
    float inv = 1.0f / fmaxf(cnt[g], 1.0f);
    float p   = pooled[g * H_DIM + lane] * inv;
    __shared__ float logits[N_CLS];
    for (int c = 0; c < N_CLS; ++c) {
        float v = p * Wl[lane * N_CLS + c];
        for (int off = 32; off; off >>= 1) v += __shfl_xor(v, off);
        if (lane == 0) logits[c] = v + bl[c];
    }
    __syncthreads();
    if (lane == 0) {
        float m = logits[0];
        for (int c = 1; c < N_CLS; ++c) m = fmaxf(m, logits[c]);
        float s = 0.f;
        for (int c = 0; c < N_CLS; ++c) s += expf(logits[c] - m);
        float ls = logf(s);
        for (int c = 0; c < N_CLS; ++c) out[g * N_CLS + c] = logits[c] - m - ls;
    }
}

// ---------------- launch ----------------

extern "C" void kernel_launch(void* const* d_in, const int* in_sizes, int n_in,
                              void* d_out, int out_size, void* d_ws, size_t ws_size,
                              hipStream_t stream) {
    const float* x     = (const float*)d_in[0];
    const int*   ei    = (const int*)d_in[1];    // int64 in ref -> int32 on device
    const int*   batch = (const int*)d_in[2];    // int64 in ref -> int32 on device
    const float* W1    = (const float*)d_in[3];
    const float* b1    = (const float*)d_in[4];
    const float* W2    = (const float*)d_in[5];
    const float* b2    = (const float*)d_in[6];
    const float* Wl    = (const float*)d_in[7];
    const float* bl    = (const float*)d_in[8];
    float*       out   = (float*)d_out;

    char* p = (char*)d_ws;
    auto alloc = [&](size_t bytes) {
        char* r = p;
        p += (bytes + 255) & ~(size_t)255;
        return r;
    };
    int*   deg    = (int*)  alloc((size_t)N_NODES * 4);
    int*   cur    = (int*)  alloc((size_t)N_NODES * 4);
    int*   rowptr = (int*)  alloc((size_t)(N_NODES + 1) * 4);
    float* dinv   = (float*)alloc((size_t)N_NODES * 4);
    int*   colsrc = (int*)  alloc((size_t)N_EDGES * 4);
    float* hA     = (float*)alloc((size_t)N_NODES * H_DIM * 4);
    float* hB     = (float*)alloc((size_t)N_NODES * H_DIM * 4);
    float* pooled = (float*)alloc((size_t)N_GRAPH * H_DIM * 4);
    float* cnt    = (float*)alloc((size_t)N_GRAPH * 4);

    hipMemsetAsync(deg, 0, (size_t)N_NODES * 4, stream);
    hipMemsetAsync(cur, 0, (size_t)N_NODES * 4, stream);
    hipMemsetAsync(pooled, 0, (size_t)N_GRAPH * H_DIM * 4, stream);
    hipMemsetAsync(cnt, 0, (size_t)N_GRAPH * 4, stream);

    int eb  = (N_EDGES + 255) / 256;
    int nb  = (N_NODES + 255) / 256;
    int nb4 = (N_NODES + 3) / 4;

    count_deg   <<<eb, 256, 0, stream>>>(ei, deg);
    compute_dinv<<<nb, 256, 0, stream>>>(deg, dinv);
    scan_deg    <<<1, 1024, 0, stream>>>(deg, rowptr);
    fill_csr    <<<eb, 256, 0, stream>>>(ei, rowptr, cur, colsrc);

    gemm_xw <<<nb4, 256, 0, stream>>>(x, W1, hA, F_IN);
    agg_norm<<<nb4, 256, 0, stream>>>(hA, dinv, rowptr, colsrc, b1, hB, 1);
    gemm_xw <<<nb4, 256, 0, stream>>>(hB, W2, hA, H_DIM);
    agg_norm<<<nb4, 256, 0, stream>>>(hA, dinv, rowptr, colsrc, b2, hB, 0);

    pool_nodes <<<nb4, 256, 0, stream>>>(hB, batch, pooled, cnt);
    head_kernel<<<N_GRAPH, 64, 0, stream>>>(pooled, cnt, Wl, bl, out);
}

// Round 3
// 669.643 us; speedup vs baseline: 1.2355x; 1.2355x over previous
//
#include <hip/hip_runtime.h>

#define N_NODES 100000
#define N_EDGES 1250000
#define F_IN    128
#define H_DIM   64
#define N_CLS   10
#define N_GRAPH 1000

#define SCAN_NB ((N_NODES + 255) / 256)   // 391

// ---------------- CSR build ----------------

__global__ void count_deg(const int* __restrict__ ei, int* __restrict__ deg) {
    int e = blockIdx.x * blockDim.x + threadIdx.x;
    if (e < N_EDGES) {
        int dst = ei[N_EDGES + e];
        atomicAdd(&deg[dst], 1);
    }
}

__global__ void compute_dinv(const int* __restrict__ deg, float* __restrict__ dinv) {
    int i = blockIdx.x * blockDim.x + threadIdx.x;
    if (i < N_NODES) dinv[i] = rsqrtf((float)deg[i] + 1.0f);  // +1 self-loop
}

// --- hierarchical exclusive scan of deg -> rowptr ---

__global__ void block_sums(const int* __restrict__ deg, int* __restrict__ bsum) {
    int i = blockIdx.x * 256 + threadIdx.x;
    int v = (i < N_NODES) ? deg[i] : 0;
    for (int off = 32; off; off >>= 1) v += __shfl_xor(v, off);
    __shared__ int ws[4];
    if ((threadIdx.x & 63) == 0) ws[threadIdx.x >> 6] = v;
    __syncthreads();
    if (threadIdx.x == 0) bsum[blockIdx.x] = ws[0] + ws[1] + ws[2] + ws[3];
}

// single block, 512 threads, scans SCAN_NB block sums (exclusive, in place)
__global__ void scan_bsums(int* __restrict__ bsum) {
    __shared__ int s[512];
    int t = threadIdx.x;
    int v = (t < SCAN_NB) ? bsum[t] : 0;
    s[t] = v;
    __syncthreads();
    for (int off = 1; off < 512; off <<= 1) {
        int u = (t >= off) ? s[t - off] : 0;
        __syncthreads();
        s[t] += u;
        __syncthreads();
    }
    if (t < SCAN_NB) bsum[t] = s[t] - v;  // exclusive prefix
}

__global__ void write_rowptr(const int* __restrict__ deg, const int* __restrict__ bsum,
                             int* __restrict__ rowptr) {
    int i    = blockIdx.x * 256 + threadIdx.x;
    int lane = threadIdx.x & 63;
    int wid  = threadIdx.x >> 6;
    int v    = (i < N_NODES) ? deg[i] : 0;
    int inc  = v;
    for (int off = 1; off < 64; off <<= 1) {
        int u = __shfl_up(inc, off);
        if (lane >= off) inc += u;
    }
    __shared__ int ws[4];
    if (lane == 63) ws[wid] = inc;
    __syncthreads();
    int woff = 0;
    for (int w = 0; w < wid; ++w) woff += ws[w];
    if (i < N_NODES) rowptr[i] = bsum[blockIdx.x] + woff + inc - v;
    if (i == 0) rowptr[N_NODES] = N_EDGES;
}

__global__ void fill_csr(const int* __restrict__ ei, const int* __restrict__ rowptr,
                         int* __restrict__ cur, int* __restrict__ colsrc) {
    int e = blockIdx.x * blockDim.x + threadIdx.x;
    if (e < N_EDGES) {
        int src = ei[e];
        int dst = ei[N_EDGES + e];
        int pos = rowptr[dst] + atomicAdd(&cur[dst], 1);
        colsrc[pos] = src;
    }
}

// ---------------- dense compute ----------------

// Y[N,64] = X[N,K] @ W[K,64]; block = 256 threads = 4 rows x 64 cols
__global__ void gemm_xw(const float* __restrict__ X, const float* __restrict__ W,
                        float* __restrict__ Y, int K) {
    __shared__ float xs[4][F_IN];
    int tid  = threadIdx.x;
    int rg   = tid >> 6;
    int lane = tid & 63;
    int row  = blockIdx.x * 4 + rg;
    if (row < N_NODES) {
        xs[rg][lane] = X[(size_t)row * K + lane];
        if (K > 64) xs[rg][lane + 64] = X[(size_t)row * K + lane + 64];
    }
    __syncthreads();
    float acc = 0.f;
    for (int k = 0; k < K; ++k)
        acc += xs[rg][k] * W[k * H_DIM + lane];
    if (row < N_NODES) Y[(size_t)row * H_DIM + lane] = acc;
}

// out[i] = [relu](sum_{e: dst=i} h[src]*dinv[src]*dinv[i] + h[i]*dinv[i]^2 + b)
__global__ void agg_norm(const float* __restrict__ Hin, const float* __restrict__ dinv,
                         const int* __restrict__ rowptr, const int* __restrict__ colsrc,
                         const float* __restrict__ bias, float* __restrict__ Hout,
                         int do_relu) {
    int tid  = threadIdx.x;
    int node = blockIdx.x * 4 + (tid >> 6);
    int lane = tid & 63;
    if (node >= N_NODES) return;
    float di  = dinv[node];
    float acc = Hin[(size_t)node * H_DIM + lane] * di * di;
    int beg = rowptr[node], end = rowptr[node + 1];
    for (int p = beg; p < end; ++p) {
        int s = colsrc[p];
        acc += Hin[(size_t)s * H_DIM + lane] * (dinv[s] * di);
    }
    acc += bias[lane];
    if (do_relu) acc = fmaxf(acc, 0.f);
    Hout[(size_t)node * H_DIM + lane] = acc;
}

// ---------------- pooling + head ----------------

__global__ void pool_nodes(const float* __restrict__ Hin, const int* __restrict__ batch,
                           float* __restrict__ pooled, float* __restrict__ cnt) {
    int tid  = threadIdx.x;
    int node = blockIdx.x * 4 + (tid >> 6);
    int lane = tid & 63;
    if (node >= N_NODES) return;
    int g = batch[node];
    atomicAdd(&pooled[g * H_DIM + lane], Hin[(size_t)node * H_DIM + lane]);
    if (lane == 0) atomicAdd(&cnt[g], 1.0f);
}

__global__ void head_kernel(const float* __restrict__ pooled, const float* __restrict__ cnt,
                            const float* __restrict__ Wl, const float* __restrict__ bl,
                            float* __restrict__ out) {
    int g    = blockIdx.x;
    int lane = threadIdx.x;  // 0..63
    float inv = 1.0f / fmaxf(cnt[g], 1.0f);
    float p   = pooled[g * H_DIM + lane] * inv;
    __shared__ float logits[N_CLS];
    for (int c = 0; c < N_CLS; ++c) {
        float v = p * Wl[lane * N_CLS + c];
        for (int off = 32; off; off >>= 1) v += __shfl_xor(v, off);
        if (lane == 0) logits[c] = v + bl[c];
    }
    __syncthreads();
    if (lane == 0) {
        float m = logits[0];
        for (int c = 1; c < N_CLS; ++c) m = fmaxf(m, logits[c]);
        float s = 0.f;
        for (int c = 0; c < N_CLS; ++c) s += expf(logits[c] - m);
        float ls = logf(s);
        for (int c = 0; c < N_CLS; ++c) out[g * N_CLS + c] = logits[c] - m - ls;
    }
}

// ---------------- launch ----------------

extern "C" void kernel_launch(void* const* d_in, const int* in_sizes, int n_in,
                              void* d_out, int out_size, void* d_ws, size_t ws_size,
                              hipStream_t stream) {
    const float* x     = (const float*)d_in[0];
    const int*   ei    = (const int*)d_in[1];    // int64 in ref -> int32 on device
    const int*   batch = (const int*)d_in[2];    // int64 in ref -> int32 on device
    const float* W1    = (const float*)d_in[3];
    const float* b1    = (const float*)d_in[4];
    const float* W2    = (const float*)d_in[5];
    const float* b2    = (const float*)d_in[6];
    const float* Wl    = (const float*)d_in[7];
    const float* bl    = (const float*)d_in[8];
    float*       out   = (float*)d_out;

    char* p = (char*)d_ws;
    auto alloc = [&](size_t bytes) {
        char* r = p;
        p += (bytes + 255) & ~(size_t)255;
        return r;
    };
    int*   deg    = (int*)  alloc((size_t)N_NODES * 4);
    int*   cur    = (int*)  alloc((size_t)N_NODES * 4);
    int*   rowptr = (int*)  alloc((size_t)(N_NODES + 1) * 4);
    int*   bsum   = (int*)  alloc((size_t)SCAN_NB * 4);
    float* dinv   = (float*)alloc((size_t)N_NODES * 4);
    int*   colsrc = (int*)  alloc((size_t)N_EDGES * 4);
    float* hA     = (float*)alloc((size_t)N_NODES * H_DIM * 4);
    float* hB     = (float*)alloc((size_t)N_NODES * H_DIM * 4);
    float* pooled = (float*)alloc((size_t)N_GRAPH * H_DIM * 4);
    float* cnt    = (float*)alloc((size_t)N_GRAPH * 4);

    hipMemsetAsync(deg, 0, (size_t)N_NODES * 4, stream);
    hipMemsetAsync(cur, 0, (size_t)N_NODES * 4, stream);
    hipMemsetAsync(pooled, 0, (size_t)N_GRAPH * H_DIM * 4, stream);
    hipMemsetAsync(cnt, 0, (size_t)N_GRAPH * 4, stream);

    int eb  = (N_EDGES + 255) / 256;
    int nb  = (N_NODES + 255) / 256;
    int nb4 = (N_NODES + 3) / 4;

    count_deg   <<<eb, 256, 0, stream>>>(ei, deg);
    compute_dinv<<<nb, 256, 0, stream>>>(deg, dinv);
    block_sums  <<<SCAN_NB, 256, 0, stream>>>(deg, bsum);
    scan_bsums  <<<1, 512, 0, stream>>>(bsum);
    write_rowptr<<<SCAN_NB, 256, 0, stream>>>(deg, bsum, rowptr);
    fill_csr    <<<eb, 256, 0, stream>>>(ei, rowptr, cur, colsrc);

    gemm_xw <<<nb4, 256, 0, stream>>>(x, W1, hA, F_IN);
    agg_norm<<<nb4, 256, 0, stream>>>(hA, dinv, rowptr, colsrc, b1, hB, 1);
    gemm_xw <<<nb4, 256, 0, stream>>>(hB, W2, hA, H_DIM);
    agg_norm<<<nb4, 256, 0, stream>>>(hA, dinv, rowptr, colsrc, b2, hB, 0);

    pool_nodes <<<nb4, 256, 0, stream>>>(hB, batch, pooled, cnt);
    head_kernel<<<N_GRAPH, 64, 0, stream>>>(pooled, cnt, Wl, bl, out);
}

// Round 4
// 546.338 us; speedup vs baseline: 1.5143x; 1.2257x over previous
//
#include <hip/hip_runtime.h>

#define N_NODES 100000
#define N_EDGES 1250000
#define F_IN    128
#define H_DIM   64
#define N_CLS   10
#define N_GRAPH 1000

#define SCAN_NB ((N_NODES + 255) / 256)   // 391

// ---------------- CSR build ----------------

__global__ void count_deg(const int* __restrict__ ei, int* __restrict__ deg) {
    int e = blockIdx.x * blockDim.x + threadIdx.x;
    if (e < N_EDGES) {
        int dst = ei[N_EDGES + e];
        atomicAdd(&deg[dst], 1);
    }
}

__global__ void compute_dinv(const int* __restrict__ deg, float* __restrict__ dinv) {
    int i = blockIdx.x * blockDim.x + threadIdx.x;
    if (i < N_NODES) dinv[i] = rsqrtf((float)deg[i] + 1.0f);  // +1 self-loop
}

// --- hierarchical exclusive scan of deg -> rowptr ---

__global__ void block_sums(const int* __restrict__ deg, int* __restrict__ bsum) {
    int i = blockIdx.x * 256 + threadIdx.x;
    int v = (i < N_NODES) ? deg[i] : 0;
    for (int off = 32; off; off >>= 1) v += __shfl_xor(v, off);
    __shared__ int ws[4];
    if ((threadIdx.x & 63) == 0) ws[threadIdx.x >> 6] = v;
    __syncthreads();
    if (threadIdx.x == 0) bsum[blockIdx.x] = ws[0] + ws[1] + ws[2] + ws[3];
}

// single block, 512 threads, scans SCAN_NB block sums (exclusive, in place)
__global__ void scan_bsums(int* __restrict__ bsum) {
    __shared__ int s[512];
    int t = threadIdx.x;
    int v = (t < SCAN_NB) ? bsum[t] : 0;
    s[t] = v;
    __syncthreads();
    for (int off = 1; off < 512; off <<= 1) {
        int u = (t >= off) ? s[t - off] : 0;
        __syncthreads();
        s[t] += u;
        __syncthreads();
    }
    if (t < SCAN_NB) bsum[t] = s[t] - v;  // exclusive prefix
}

__global__ void write_rowptr(const int* __restrict__ deg, const int* __restrict__ bsum,
                             int* __restrict__ rowptr) {
    int i    = blockIdx.x * 256 + threadIdx.x;
    int lane = threadIdx.x & 63;
    int wid  = threadIdx.x >> 6;
    int v    = (i < N_NODES) ? deg[i] : 0;
    int inc  = v;
    for (int off = 1; off < 64; off <<= 1) {
        int u = __shfl_up(inc, off);
        if (lane >= off) inc += u;
    }
    __shared__ int ws[4];
    if (lane == 63) ws[wid] = inc;
    __syncthreads();
    int woff = 0;
    for (int w = 0; w < wid; ++w) woff += ws[w];
    if (i < N_NODES) rowptr[i] = bsum[blockIdx.x] + woff + inc - v;
    if (i == 0) rowptr[N_NODES] = N_EDGES;
}

__global__ void fill_csr(const int* __restrict__ ei, const int* __restrict__ rowptr,
                         int* __restrict__ cur, int* __restrict__ colsrc) {
    int e = blockIdx.x * blockDim.x + threadIdx.x;
    if (e < N_EDGES) {
        int src = ei[e];
        int dst = ei[N_EDGES + e];
        int pos = rowptr[dst] + atomicAdd(&cur[dst], 1);
        colsrc[pos] = src;
    }
}

// ---------------- dense compute ----------------

// Y[N,64] = X[N,K] @ W[K,64]; block = 256 threads = 4 rows x 64 cols
__global__ void gemm_xw(const float* __restrict__ X, const float* __restrict__ W,
                        float* __restrict__ Y, int K) {
    __shared__ float xs[4][F_IN];
    int tid  = threadIdx.x;
    int rg   = tid >> 6;
    int lane = tid & 63;
    int row  = blockIdx.x * 4 + rg;
    if (row < N_NODES) {
        xs[rg][lane] = X[(size_t)row * K + lane];
        if (K > 64) xs[rg][lane + 64] = X[(size_t)row * K + lane + 64];
    }
    __syncthreads();
    float acc = 0.f;
    for (int k = 0; k < K; ++k)
        acc += xs[rg][k] * W[k * H_DIM + lane];
    if (row < N_NODES) Y[(size_t)row * H_DIM + lane] = acc;
}

// out[i] = [relu](sum_{e: dst=i} h[src]*dinv[src]*dinv[i] + h[i]*dinv[i]^2 + b)
__global__ void agg_norm(const float* __restrict__ Hin, const float* __restrict__ dinv,
                         const int* __restrict__ rowptr, const int* __restrict__ colsrc,
                         const float* __restrict__ bias, float* __restrict__ Hout,
                         int do_relu) {
    int tid  = threadIdx.x;
    int node = blockIdx.x * 4 + (tid >> 6);
    int lane = tid & 63;
    if (node >= N_NODES) return;
    float di  = dinv[node];
    float acc = Hin[(size_t)node * H_DIM + lane] * di * di;
    int beg = rowptr[node], end = rowptr[node + 1];
    for (int p = beg; p < end; ++p) {
        int s = colsrc[p];
        acc += Hin[(size_t)s * H_DIM + lane] * (dinv[s] * di);
    }
    acc += bias[lane];
    if (do_relu) acc = fmaxf(acc, 0.f);
    Hout[(size_t)node * H_DIM + lane] = acc;
}

// ---------------- fused pooling + head ----------------
// batch is SORTED: graph g's nodes are a contiguous segment. One block per
// graph: binary-search the segment, coalesced segment-sum (no atomics), then
// the linear head + log_softmax.
__global__ void pool_head(const float* __restrict__ Hin, const int* __restrict__ batch,
                          const float* __restrict__ Wl, const float* __restrict__ bl,
                          float* __restrict__ out) {
    int g    = blockIdx.x;
    int tid  = threadIdx.x;   // 0..255
    int rg   = tid >> 6;
    int lane = tid & 63;

    // lower_bound(batch, key) — wave-uniform scalar loads (broadcast)
    auto lb = [&](int key) {
        int lo = 0, hi = N_NODES;
        while (lo < hi) {
            int mid = (lo + hi) >> 1;
            if (batch[mid] < key) lo = mid + 1; else hi = mid;
        }
        return lo;
    };
    int beg = lb(g);
    int end = lb(g + 1);

    float acc = 0.f;
    for (int i = beg + rg; i < end; i += 4)
        acc += Hin[(size_t)i * H_DIM + lane];

    __shared__ float s[4][H_DIM];
    s[rg][lane] = acc;
    __syncthreads();

    if (rg == 0) {
        float p = s[0][lane] + s[1][lane] + s[2][lane] + s[3][lane];
        p *= 1.0f / fmaxf((float)(end - beg), 1.0f);

        __shared__ float logits[N_CLS];
        for (int c = 0; c < N_CLS; ++c) {
            float v = p * Wl[lane * N_CLS + c];
            for (int off = 32; off; off >>= 1) v += __shfl_xor(v, off);
            if (lane == 0) logits[c] = v + bl[c];
        }
        if (lane == 0) {
            float m = logits[0];
            for (int c = 1; c < N_CLS; ++c) m = fmaxf(m, logits[c]);
            float sum = 0.f;
            for (int c = 0; c < N_CLS; ++c) sum += expf(logits[c] - m);
            float ls = logf(sum);
            for (int c = 0; c < N_CLS; ++c) out[g * N_CLS + c] = logits[c] - m - ls;
        }
    }
}

// ---------------- launch ----------------

extern "C" void kernel_launch(void* const* d_in, const int* in_sizes, int n_in,
                              void* d_out, int out_size, void* d_ws, size_t ws_size,
                              hipStream_t stream) {
    const float* x     = (const float*)d_in[0];
    const int*   ei    = (const int*)d_in[1];    // int64 in ref -> int32 on device
    const int*   batch = (const int*)d_in[2];    // int64 in ref -> int32 on device
    const float* W1    = (const float*)d_in[3];
    const float* b1    = (const float*)d_in[4];
    const float* W2    = (const float*)d_in[5];
    const float* b2    = (const float*)d_in[6];
    const float* Wl    = (const float*)d_in[7];
    const float* bl    = (const float*)d_in[8];
    float*       out   = (float*)d_out;

    char* p = (char*)d_ws;
    auto alloc = [&](size_t bytes) {
        char* r = p;
        p += (bytes + 255) & ~(size_t)255;
        return r;
    };
    int*   deg    = (int*)  alloc((size_t)N_NODES * 4);
    int*   cur    = (int*)  alloc((size_t)N_NODES * 4);
    int*   rowptr = (int*)  alloc((size_t)(N_NODES + 1) * 4);
    int*   bsum   = (int*)  alloc((size_t)SCAN_NB * 4);
    float* dinv   = (float*)alloc((size_t)N_NODES * 4);
    int*   colsrc = (int*)  alloc((size_t)N_EDGES * 4);
    float* hA     = (float*)alloc((size_t)N_NODES * H_DIM * 4);
    float* hB     = (float*)alloc((size_t)N_NODES * H_DIM * 4);

    hipMemsetAsync(deg, 0, (size_t)N_NODES * 4, stream);
    hipMemsetAsync(cur, 0, (size_t)N_NODES * 4, stream);

    int eb  = (N_EDGES + 255) / 256;
    int nb  = (N_NODES + 255) / 256;
    int nb4 = (N_NODES + 3) / 4;

    count_deg   <<<eb, 256, 0, stream>>>(ei, deg);
    compute_dinv<<<nb, 256, 0, stream>>>(deg, dinv);
    block_sums  <<<SCAN_NB, 256, 0, stream>>>(deg, bsum);
    scan_bsums  <<<1, 512, 0, stream>>>(bsum);
    write_rowptr<<<SCAN_NB, 256, 0, stream>>>(deg, bsum, rowptr);
    fill_csr    <<<eb, 256, 0, stream>>>(ei, rowptr, cur, colsrc);

    gemm_xw <<<nb4, 256, 0, stream>>>(x, W1, hA, F_IN);
    agg_norm<<<nb4, 256, 0, stream>>>(hA, dinv, rowptr, colsrc, b1, hB, 1);
    gemm_xw <<<nb4, 256, 0, stream>>>(hB, W2, hA, H_DIM);
    agg_norm<<<nb4, 256, 0, stream>>>(hA, dinv, rowptr, colsrc, b2, hB, 0);

    pool_head<<<N_GRAPH, 256, 0, stream>>>(hB, batch, Wl, bl, out);
}

// Round 5
// 411.959 us; speedup vs baseline: 2.0083x; 1.3262x over previous
//
#include <hip/hip_runtime.h>

#define N_NODES 100000
#define N_EDGES 1250000
#define F_IN    128
#define H_DIM   64
#define N_CLS   10
#define N_GRAPH 1000

#define SCAN_NB ((N_NODES + 255) / 256)   // 391

typedef __attribute__((ext_vector_type(8))) short bf16x8;
typedef __attribute__((ext_vector_type(4))) float f32x4;

__device__ __forceinline__ unsigned short f2bf(float f) {  // RNE fp32 -> bf16
    unsigned int u = __builtin_bit_cast(unsigned int, f);
    u += 0x7FFFu + ((u >> 16) & 1u);
    return (unsigned short)(u >> 16);
}
__device__ __forceinline__ float bf2f(unsigned short h) {
    unsigned int u = (unsigned int)h << 16;
    return __builtin_bit_cast(float, u);
}

// ---------------- CSR build ----------------

__global__ void count_deg(const int* __restrict__ ei, int* __restrict__ deg) {
    int e = blockIdx.x * blockDim.x + threadIdx.x;
    if (e < N_EDGES) {
        int dst = ei[N_EDGES + e];
        atomicAdd(&deg[dst], 1);
    }
}

__global__ void compute_dinv(const int* __restrict__ deg, float* __restrict__ dinv) {
    int i = blockIdx.x * blockDim.x + threadIdx.x;
    if (i < N_NODES) dinv[i] = rsqrtf((float)deg[i] + 1.0f);  // +1 self-loop
}

__global__ void block_sums(const int* __restrict__ deg, int* __restrict__ bsum) {
    int i = blockIdx.x * 256 + threadIdx.x;
    int v = (i < N_NODES) ? deg[i] : 0;
    for (int off = 32; off; off >>= 1) v += __shfl_xor(v, off);
    __shared__ int ws[4];
    if ((threadIdx.x & 63) == 0) ws[threadIdx.x >> 6] = v;
    __syncthreads();
    if (threadIdx.x == 0) bsum[blockIdx.x] = ws[0] + ws[1] + ws[2] + ws[3];
}

__global__ void scan_bsums(int* __restrict__ bsum) {
    __shared__ int s[512];
    int t = threadIdx.x;
    int v = (t < SCAN_NB) ? bsum[t] : 0;
    s[t] = v;
    __syncthreads();
    for (int off = 1; off < 512; off <<= 1) {
        int u = (t >= off) ? s[t - off] : 0;
        __syncthreads();
        s[t] += u;
        __syncthreads();
    }
    if (t < SCAN_NB) bsum[t] = s[t] - v;  // exclusive prefix
}

__global__ void write_rowptr(const int* __restrict__ deg, const int* __restrict__ bsum,
                             int* __restrict__ rowptr, int* __restrict__ cur) {
    int i    = blockIdx.x * 256 + threadIdx.x;
    int lane = threadIdx.x & 63;
    int wid  = threadIdx.x >> 6;
    int v    = (i < N_NODES) ? deg[i] : 0;
    int inc  = v;
    for (int off = 1; off < 64; off <<= 1) {
        int u = __shfl_up(inc, off);
        if (lane >= off) inc += u;
    }
    __shared__ int ws[4];
    if (lane == 63) ws[wid] = inc;
    __syncthreads();
    int woff = 0;
    for (int w = 0; w < wid; ++w) woff += ws[w];
    if (i < N_NODES) {
        rowptr[i] = bsum[blockIdx.x] + woff + inc - v;
        cur[i] = 0;
    }
    if (i == 0) rowptr[N_NODES] = N_EDGES;
}

__global__ void fill_csr(const int* __restrict__ ei, const int* __restrict__ rowptr,
                         int* __restrict__ cur, int* __restrict__ colsrc) {
    int e = blockIdx.x * blockDim.x + threadIdx.x;
    if (e < N_EDGES) {
        int src = ei[e];
        int dst = ei[N_EDGES + e];
        int pos = rowptr[dst] + atomicAdd(&cur[dst], 1);
        colsrc[pos] = src;
    }
}

// ---------------- weight packing (fp32 -> bf16 MFMA B-fragment order) ----------------
// B-frag for (col-tile t, k-chunk c): lane l, elem j holds W[c*32 + (l>>4)*8 + j][t*16 + (l&15)]
// Packed at Wp[((t*(K/32)+c)*64 + l)*8 + j].

__global__ void pack_weights(const float* __restrict__ W1, const float* __restrict__ W2,
                             unsigned short* __restrict__ Wp1, unsigned short* __restrict__ Wp2) {
    int idx = blockIdx.x * 256 + threadIdx.x;   // 0..1535
    if (idx < 1024) {                           // W1: K=128 -> 4 chunks x 4 tiles
        int l = idx & 63, tc = idx >> 6;
        int c = tc & 3, t = tc >> 2;
        for (int j = 0; j < 8; ++j)
            Wp1[idx * 8 + j] = f2bf(W1[(c * 32 + (l >> 4) * 8 + j) * H_DIM + t * 16 + (l & 15)]);
    } else if (idx < 1536) {                    // W2: K=64 -> 2 chunks x 4 tiles
        int i2 = idx - 1024;
        int l = i2 & 63, tc = i2 >> 6;
        int c = tc & 1, t = tc >> 1;
        for (int j = 0; j < 8; ++j)
            Wp2[i2 * 8 + j] = f2bf(W2[(c * 32 + (l >> 4) * 8 + j) * H_DIM + t * 16 + (l & 15)]);
    }
}

// ---------------- MFMA GEMM:  Y[row][col] = (A[row][:] @ W[:,col]) * dinv[row]  (bf16 out) ----
// Block = 256 threads = 4 waves; wave w owns rows [blk*64 + w*16, +16), all 64 cols.

template<int K, bool ABF>
__global__ void gemm_mfma(const void* __restrict__ Ap, const unsigned short* __restrict__ Wp,
                          const float* __restrict__ dinv, unsigned short* __restrict__ Y) {
    int lane = threadIdx.x & 63;
    int wave = threadIdx.x >> 6;
    int l16 = lane & 15, lhi = lane >> 4;
    int row0 = blockIdx.x * 64 + wave * 16;
    int arow = row0 + l16;
    bool aok = (arow < N_NODES);

    f32x4 acc[4];
#pragma unroll
    for (int t = 0; t < 4; ++t) acc[t] = (f32x4){0.f, 0.f, 0.f, 0.f};

#pragma unroll
    for (int c = 0; c < K / 32; ++c) {
        bf16x8 a;
        if (ABF) {
            if (aok) a = *(const bf16x8*)((const unsigned short*)Ap + (size_t)arow * K + c * 32 + lhi * 8);
            else     a = (bf16x8){0, 0, 0, 0, 0, 0, 0, 0};
        } else {
            if (aok) {
                const float* Af = (const float*)Ap + (size_t)arow * K + c * 32 + lhi * 8;
                float4 f0 = *(const float4*)(Af);
                float4 f1 = *(const float4*)(Af + 4);
                a = (bf16x8){(short)f2bf(f0.x), (short)f2bf(f0.y), (short)f2bf(f0.z), (short)f2bf(f0.w),
                             (short)f2bf(f1.x), (short)f2bf(f1.y), (short)f2bf(f1.z), (short)f2bf(f1.w)};
            } else a = (bf16x8){0, 0, 0, 0, 0, 0, 0, 0};
        }
#pragma unroll
        for (int t = 0; t < 4; ++t) {
            bf16x8 b = *(const bf16x8*)(Wp + ((size_t)(t * (K / 32) + c) * 64 + lane) * 8);
            acc[t] = __builtin_amdgcn_mfma_f32_16x16x32_bf16(a, b, acc[t], 0, 0, 0);
        }
    }

#pragma unroll
    for (int r = 0; r < 4; ++r) {
        int row = row0 + lhi * 4 + r;
        if (row < N_NODES) {
            float dv = dinv[row];
#pragma unroll
            for (int t = 0; t < 4; ++t)
                Y[(size_t)row * H_DIM + t * 16 + l16] = f2bf(acc[t][r] * dv);
        }
    }
}

// ---------------- aggregation (gather, bf16 source pre-scaled by dinv[src]) ----------------
// out[i] = dinv[i] * (sum_{e: dst=i} h'[src] + h'[i]) + b    [h' = h * dinv]

__global__ void agg1_relu(const unsigned short* __restrict__ Hb, const float* __restrict__ dinv,
                          const int* __restrict__ rowptr, const int* __restrict__ colsrc,
                          const float* __restrict__ bias, unsigned short* __restrict__ Z) {
    int tid  = threadIdx.x;
    int node = blockIdx.x * 4 + (tid >> 6);
    int lane = tid & 63;
    if (node >= N_NODES) return;
    float acc = bf2f(Hb[(size_t)node * H_DIM + lane]);   // self term (already has dinv[node])
    int beg = rowptr[node], end = rowptr[node + 1];
    for (int p = beg; p < end; ++p) {
        int s = colsrc[p];
        acc += bf2f(Hb[(size_t)s * H_DIM + lane]);
    }
    float r = fmaxf(acc * dinv[node] + bias[lane], 0.f);
    Z[(size_t)node * H_DIM + lane] = f2bf(r);
}

__global__ void agg2(const unsigned short* __restrict__ Hb, const float* __restrict__ dinv,
                     const int* __restrict__ rowptr, const int* __restrict__ colsrc,
                     const float* __restrict__ bias, unsigned short* __restrict__ Z) {
    int tid  = threadIdx.x;
    int node = blockIdx.x * 4 + (tid >> 6);
    int lane = tid & 63;
    if (node >= N_NODES) return;
    float acc = bf2f(Hb[(size_t)node * H_DIM + lane]);
    int beg = rowptr[node], end = rowptr[node + 1];
    for (int p = beg; p < end; ++p) {
        int s = colsrc[p];
        acc += bf2f(Hb[(size_t)s * H_DIM + lane]);
    }
    Z[(size_t)node * H_DIM + lane] = f2bf(acc * dinv[node] + bias[lane]);
}

// ---------------- fused pooling + head (batch sorted -> contiguous segments) ----------------

__global__ void pool_head(const unsigned short* __restrict__ Hb, const int* __restrict__ batch,
                          const float* __restrict__ Wl, const float* __restrict__ bl,
                          float* __restrict__ out) {
    int g    = blockIdx.x;
    int tid  = threadIdx.x;   // 0..255
    int rg   = tid >> 6;
    int lane = tid & 63;

    auto lb = [&](int key) {
        int lo = 0, hi = N_NODES;
        while (lo < hi) {
            int mid = (lo + hi) >> 1;
            if (batch[mid] < key) lo = mid + 1; else hi = mid;
        }
        return lo;
    };
    int beg = lb(g);
    int end = lb(g + 1);

    float acc = 0.f;
    for (int i = beg + rg; i < end; i += 4)
        acc += bf2f(Hb[(size_t)i * H_DIM + lane]);

    __shared__ float s[4][H_DIM];
    s[rg][lane] = acc;
    __syncthreads();

    if (rg == 0) {
        float p = s[0][lane] + s[1][lane] + s[2][lane] + s[3][lane];
        p *= 1.0f / fmaxf((float)(end - beg), 1.0f);

        __shared__ float logits[N_CLS];
        for (int c = 0; c < N_CLS; ++c) {
            float v = p * Wl[lane * N_CLS + c];
            for (int off = 32; off; off >>= 1) v += __shfl_xor(v, off);
            if (lane == 0) logits[c] = v + bl[c];
        }
        if (lane == 0) {
            float m = logits[0];
            for (int c = 1; c < N_CLS; ++c) m = fmaxf(m, logits[c]);
            float sum = 0.f;
            for (int c = 0; c < N_CLS; ++c) sum += expf(logits[c] - m);
            float ls = logf(sum);
            for (int c = 0; c < N_CLS; ++c) out[g * N_CLS + c] = logits[c] - m - ls;
        }
    }
}

// ---------------- launch ----------------

extern "C" void kernel_launch(void* const* d_in, const int* in_sizes, int n_in,
                              void* d_out, int out_size, void* d_ws, size_t ws_size,
                              hipStream_t stream) {
    const float* x     = (const float*)d_in[0];
    const int*   ei    = (const int*)d_in[1];
    const int*   batch = (const int*)d_in[2];
    const float* W1    = (const float*)d_in[3];
    const float* b1    = (const float*)d_in[4];
    const float* W2    = (const float*)d_in[5];
    const float* b2    = (const float*)d_in[6];
    const float* Wl    = (const float*)d_in[7];
    const float* bl    = (const float*)d_in[8];
    float*       out   = (float*)d_out;

    char* p = (char*)d_ws;
    auto alloc = [&](size_t bytes) {
        char* r = p;
        p += (bytes + 255) & ~(size_t)255;
        return r;
    };
    int*            deg    = (int*)            alloc((size_t)N_NODES * 4);
    int*            cur    = (int*)            alloc((size_t)N_NODES * 4);
    int*            rowptr = (int*)            alloc((size_t)(N_NODES + 1) * 4);
    int*            bsum   = (int*)            alloc((size_t)SCAN_NB * 4);
    float*          dinv   = (float*)          alloc((size_t)N_NODES * 4);
    int*            colsrc = (int*)            alloc((size_t)N_EDGES * 4);
    unsigned short* hA     = (unsigned short*) alloc((size_t)N_NODES * H_DIM * 2);
    unsigned short* hB     = (unsigned short*) alloc((size_t)N_NODES * H_DIM * 2);
    unsigned short* Wp1    = (unsigned short*) alloc((size_t)1024 * 8 * 2);
    unsigned short* Wp2    = (unsigned short*) alloc((size_t)512 * 8 * 2);

    hipMemsetAsync(deg, 0, (size_t)N_NODES * 4, stream);

    int eb  = (N_EDGES + 255) / 256;
    int nb  = (N_NODES + 255) / 256;
    int nb4 = (N_NODES + 3) / 4;
    int gb  = (N_NODES + 63) / 64;   // MFMA gemm blocks (64 rows each)

    count_deg   <<<eb, 256, 0, stream>>>(ei, deg);
    compute_dinv<<<nb, 256, 0, stream>>>(deg, dinv);
    block_sums  <<<SCAN_NB, 256, 0, stream>>>(deg, bsum);
    scan_bsums  <<<1, 512, 0, stream>>>(bsum);
    write_rowptr<<<SCAN_NB, 256, 0, stream>>>(deg, bsum, rowptr, cur);
    fill_csr    <<<eb, 256, 0, stream>>>(ei, rowptr, cur, colsrc);
    pack_weights<<<6, 256, 0, stream>>>(W1, W2, Wp1, Wp2);

    gemm_mfma<F_IN, false><<<gb, 256, 0, stream>>>(x, Wp1, dinv, hA);    // h1' = (x@W1)*dinv
    agg1_relu<<<nb4, 256, 0, stream>>>(hA, dinv, rowptr, colsrc, b1, hB); // z1 = relu(agg+b1)
    gemm_mfma<H_DIM, true><<<gb, 256, 0, stream>>>(hB, Wp2, dinv, hA);   // h2' = (z1@W2)*dinv
    agg2     <<<nb4, 256, 0, stream>>>(hA, dinv, rowptr, colsrc, b2, hB); // z2 = agg+b2
    pool_head<<<N_GRAPH, 256, 0, stream>>>(hB, batch, Wl, bl, out);
}

// Round 6
// 273.901 us; speedup vs baseline: 3.0206x; 1.5040x over previous
//
#include <hip/hip_runtime.h>

#define N_NODES 100000
#define N_EDGES 1250000
#define F_IN    128
#define H_DIM   64
#define N_CLS   10
#define N_GRAPH 1000

#define SCAN_NB ((N_NODES + 255) / 256)   // 391

typedef __attribute__((ext_vector_type(8))) short bf16x8;
typedef __attribute__((ext_vector_type(4))) float f32x4;

__device__ __forceinline__ unsigned short f2bf(float f) {  // RNE fp32 -> bf16
    unsigned int u = __builtin_bit_cast(unsigned int, f);
    u += 0x7FFFu + ((u >> 16) & 1u);
    return (unsigned short)(u >> 16);
}
__device__ __forceinline__ float bf2f(unsigned short h) {
    unsigned int u = (unsigned int)h << 16;
    return __builtin_bit_cast(float, u);
}
__device__ __forceinline__ float bflo(unsigned int g) { return bf2f((unsigned short)(g & 0xFFFFu)); }
__device__ __forceinline__ float bfhi(unsigned int g) { return bf2f((unsigned short)(g >> 16)); }

// ---------------- CSR build ----------------

__global__ void count_deg(const int* __restrict__ ei, int* __restrict__ deg) {
    int e = blockIdx.x * blockDim.x + threadIdx.x;
    if (e < N_EDGES) {
        int dst = ei[N_EDGES + e];
        atomicAdd(&deg[dst], 1);
    }
}

__global__ void compute_dinv(const int* __restrict__ deg, float* __restrict__ dinv) {
    int i = blockIdx.x * blockDim.x + threadIdx.x;
    if (i < N_NODES) dinv[i] = rsqrtf((float)deg[i] + 1.0f);  // +1 self-loop
}

__global__ void block_sums(const int* __restrict__ deg, int* __restrict__ bsum) {
    int i = blockIdx.x * 256 + threadIdx.x;
    int v = (i < N_NODES) ? deg[i] : 0;
    for (int off = 32; off; off >>= 1) v += __shfl_xor(v, off);
    __shared__ int ws[4];
    if ((threadIdx.x & 63) == 0) ws[threadIdx.x >> 6] = v;
    __syncthreads();
    if (threadIdx.x == 0) bsum[blockIdx.x] = ws[0] + ws[1] + ws[2] + ws[3];
}

__global__ void scan_bsums(int* __restrict__ bsum) {
    __shared__ int s[512];
    int t = threadIdx.x;
    int v = (t < SCAN_NB) ? bsum[t] : 0;
    s[t] = v;
    __syncthreads();
    for (int off = 1; off < 512; off <<= 1) {
        int u = (t >= off) ? s[t - off] : 0;
        __syncthreads();
        s[t] += u;
        __syncthreads();
    }
    if (t < SCAN_NB) bsum[t] = s[t] - v;  // exclusive prefix
}

__global__ void write_rowptr(const int* __restrict__ deg, const int* __restrict__ bsum,
                             int* __restrict__ rowptr, int* __restrict__ cur) {
    int i    = blockIdx.x * 256 + threadIdx.x;
    int lane = threadIdx.x & 63;
    int wid  = threadIdx.x >> 6;
    int v    = (i < N_NODES) ? deg[i] : 0;
    int inc  = v;
    for (int off = 1; off < 64; off <<= 1) {
        int u = __shfl_up(inc, off);
        if (lane >= off) inc += u;
    }
    __shared__ int ws[4];
    if (lane == 63) ws[wid] = inc;
    __syncthreads();
    int woff = 0;
    for (int w = 0; w < wid; ++w) woff += ws[w];
    if (i < N_NODES) {
        rowptr[i] = bsum[blockIdx.x] + woff + inc - v;
        cur[i] = 0;
    }
    if (i == 0) rowptr[N_NODES] = N_EDGES;
}

__global__ void fill_csr(const int* __restrict__ ei, const int* __restrict__ rowptr,
                         int* __restrict__ cur, int* __restrict__ colsrc) {
    int e = blockIdx.x * blockDim.x + threadIdx.x;
    if (e < N_EDGES) {
        int src = ei[e];
        int dst = ei[N_EDGES + e];
        int pos = rowptr[dst] + atomicAdd(&cur[dst], 1);
        colsrc[pos] = src;
    }
}

// ---------------- weight packing (fp32 -> bf16 MFMA B-fragment order) ----------------

__global__ void pack_weights(const float* __restrict__ W1, const float* __restrict__ W2,
                             unsigned short* __restrict__ Wp1, unsigned short* __restrict__ Wp2) {
    int idx = blockIdx.x * 256 + threadIdx.x;   // 0..1535
    if (idx < 1024) {                           // W1: K=128 -> 4 chunks x 4 tiles
        int l = idx & 63, tc = idx >> 6;
        int c = tc & 3, t = tc >> 2;
        for (int j = 0; j < 8; ++j)
            Wp1[idx * 8 + j] = f2bf(W1[(c * 32 + (l >> 4) * 8 + j) * H_DIM + t * 16 + (l & 15)]);
    } else if (idx < 1536) {                    // W2: K=64 -> 2 chunks x 4 tiles
        int i2 = idx - 1024;
        int l = i2 & 63, tc = i2 >> 6;
        int c = tc & 1, t = tc >> 1;
        for (int j = 0; j < 8; ++j)
            Wp2[i2 * 8 + j] = f2bf(W2[(c * 32 + (l >> 4) * 8 + j) * H_DIM + t * 16 + (l & 15)]);
    }
}

// ---------------- MFMA GEMM:  Y[row][col] = (A[row][:] @ W[:,col]) * dinv[row]  (bf16 out) ----

template<int K, bool ABF>
__global__ void gemm_mfma(const void* __restrict__ Ap, const unsigned short* __restrict__ Wp,
                          const float* __restrict__ dinv, unsigned short* __restrict__ Y) {
    int lane = threadIdx.x & 63;
    int wave = threadIdx.x >> 6;
    int l16 = lane & 15, lhi = lane >> 4;
    int row0 = blockIdx.x * 64 + wave * 16;
    int arow = row0 + l16;
    bool aok = (arow < N_NODES);

    f32x4 acc[4];
#pragma unroll
    for (int t = 0; t < 4; ++t) acc[t] = (f32x4){0.f, 0.f, 0.f, 0.f};

#pragma unroll
    for (int c = 0; c < K / 32; ++c) {
        bf16x8 a;
        if (ABF) {
            if (aok) a = *(const bf16x8*)((const unsigned short*)Ap + (size_t)arow * K + c * 32 + lhi * 8);
            else     a = (bf16x8){0, 0, 0, 0, 0, 0, 0, 0};
        } else {
            if (aok) {
                const float* Af = (const float*)Ap + (size_t)arow * K + c * 32 + lhi * 8;
                float4 f0 = *(const float4*)(Af);
                float4 f1 = *(const float4*)(Af + 4);
                a = (bf16x8){(short)f2bf(f0.x), (short)f2bf(f0.y), (short)f2bf(f0.z), (short)f2bf(f0.w),
                             (short)f2bf(f1.x), (short)f2bf(f1.y), (short)f2bf(f1.z), (short)f2bf(f1.w)};
            } else a = (bf16x8){0, 0, 0, 0, 0, 0, 0, 0};
        }
#pragma unroll
        for (int t = 0; t < 4; ++t) {
            bf16x8 b = *(const bf16x8*)(Wp + ((size_t)(t * (K / 32) + c) * 64 + lane) * 8);
            acc[t] = __builtin_amdgcn_mfma_f32_16x16x32_bf16(a, b, acc[t], 0, 0, 0);
        }
    }

#pragma unroll
    for (int r = 0; r < 4; ++r) {
        int row = row0 + lhi * 4 + r;
        if (row < N_NODES) {
            float dv = dinv[row];
#pragma unroll
            for (int t = 0; t < 4; ++t)
                Y[(size_t)row * H_DIM + t * 16 + l16] = f2bf(acc[t][r] * dv);
        }
    }
}

// ---------------- aggregation (gather, latency-optimized) ----------------
// Layout: 2 bf16 features per lane (uint), 32 lanes per row -> each 64-lane
// wave gathers TWO edges per instruction (half = lane>>5). Unroll 4 -> 8
// edges in flight. Tail is a single masked round (safe index, predicated add).
// out[i] = dinv[i]*(sum_{e:dst=i} h'[src] + h'[i]) + b, h' = h*dinv (pre-scaled)

template<int RELU>
__global__ void agg_fast(const unsigned short* __restrict__ Hb, const float* __restrict__ dinv,
                         const int* __restrict__ rowptr, const int* __restrict__ colsrc,
                         const float* __restrict__ bias, unsigned short* __restrict__ Z) {
    int tid  = threadIdx.x;
    int node = blockIdx.x * 4 + (tid >> 6);
    int lane = tid & 63;
    if (node >= N_NODES) return;
    int half = lane >> 5;           // which of the 2 concurrent edges
    int fp   = lane & 31;           // feature-pair index (features 2fp, 2fp+1)

    const unsigned int* H32 = (const unsigned int*)Hb;

    float ax = 0.f, ay = 0.f;
    if (half == 0) {                // self term once
        unsigned int g = H32[(size_t)node * 32 + fp];
        ax = bflo(g); ay = bfhi(g);
    }

    int beg = rowptr[node], end = rowptr[node + 1];
    int p = beg;
    for (; p + 8 <= end; p += 8) {
        int s0 = colsrc[p + half];
        int s1 = colsrc[p + 2 + half];
        int s2 = colsrc[p + 4 + half];
        int s3 = colsrc[p + 6 + half];
        unsigned int g0 = H32[(size_t)s0 * 32 + fp];
        unsigned int g1 = H32[(size_t)s1 * 32 + fp];
        unsigned int g2 = H32[(size_t)s2 * 32 + fp];
        unsigned int g3 = H32[(size_t)s3 * 32 + fp];
        ax += bflo(g0) + bflo(g1) + bflo(g2) + bflo(g3);
        ay += bfhi(g0) + bfhi(g1) + bfhi(g2) + bfhi(g3);
    }
    {   // masked tail: < 8 edges remain; issue all gathers, predicate the adds
        int e0 = p + half;
        int s0 = (e0     < end) ? colsrc[e0]     : -1;
        int s1 = (e0 + 2 < end) ? colsrc[e0 + 2] : -1;
        int s2 = (e0 + 4 < end) ? colsrc[e0 + 4] : -1;
        int s3 = (e0 + 6 < end) ? colsrc[e0 + 6] : -1;
        unsigned int g0 = H32[(size_t)(s0 < 0 ? 0 : s0) * 32 + fp];
        unsigned int g1 = H32[(size_t)(s1 < 0 ? 0 : s1) * 32 + fp];
        unsigned int g2 = H32[(size_t)(s2 < 0 ? 0 : s2) * 32 + fp];
        unsigned int g3 = H32[(size_t)(s3 < 0 ? 0 : s3) * 32 + fp];
        if (s0 >= 0) { ax += bflo(g0); ay += bfhi(g0); }
        if (s1 >= 0) { ax += bflo(g1); ay += bfhi(g1); }
        if (s2 >= 0) { ax += bflo(g2); ay += bfhi(g2); }
        if (s3 >= 0) { ax += bflo(g3); ay += bfhi(g3); }
    }

    // combine the two edge-halves (same features, different edges)
    ax += __shfl_xor(ax, 32);
    ay += __shfl_xor(ay, 32);

    if (half == 0) {
        float dv = dinv[node];
        float2 bb = *(const float2*)(bias + 2 * fp);
        float vx = ax * dv + bb.x;
        float vy = ay * dv + bb.y;
        if (RELU) { vx = fmaxf(vx, 0.f); vy = fmaxf(vy, 0.f); }
        unsigned int pk = (unsigned int)f2bf(vx) | ((unsigned int)f2bf(vy) << 16);
        *(((unsigned int*)Z) + (size_t)node * 32 + fp) = pk;
    }
}

// ---------------- fused pooling + head (batch sorted -> contiguous segments) ----------------

__global__ void pool_head(const unsigned short* __restrict__ Hb, const int* __restrict__ batch,
                          const float* __restrict__ Wl, const float* __restrict__ bl,
                          float* __restrict__ out) {
    int g    = blockIdx.x;
    int tid  = threadIdx.x;   // 0..255
    int rg   = tid >> 6;
    int lane = tid & 63;

    auto lb = [&](int key) {
        int lo = 0, hi = N_NODES;
        while (lo < hi) {
            int mid = (lo + hi) >> 1;
            if (batch[mid] < key) lo = mid + 1; else hi = mid;
        }
        return lo;
    };
    int beg = lb(g);
    int end = lb(g + 1);

    float acc = 0.f;
    for (int i = beg + rg; i < end; i += 4)
        acc += bf2f(Hb[(size_t)i * H_DIM + lane]);

    __shared__ float s[4][H_DIM];
    s[rg][lane] = acc;
    __syncthreads();

    if (rg == 0) {
        float p = s[0][lane] + s[1][lane] + s[2][lane] + s[3][lane];
        p *= 1.0f / fmaxf((float)(end - beg), 1.0f);

        __shared__ float logits[N_CLS];
        for (int c = 0; c < N_CLS; ++c) {
            float v = p * Wl[lane * N_CLS + c];
            for (int off = 32; off; off >>= 1) v += __shfl_xor(v, off);
            if (lane == 0) logits[c] = v + bl[c];
        }
        if (lane == 0) {
            float m = logits[0];
            for (int c = 1; c < N_CLS; ++c) m = fmaxf(m, logits[c]);
            float sum = 0.f;
            for (int c = 0; c < N_CLS; ++c) sum += expf(logits[c] - m);
            float ls = logf(sum);
            for (int c = 0; c < N_CLS; ++c) out[g * N_CLS + c] = logits[c] - m - ls;
        }
    }
}

// ---------------- launch ----------------

extern "C" void kernel_launch(void* const* d_in, const int* in_sizes, int n_in,
                              void* d_out, int out_size, void* d_ws, size_t ws_size,
                              hipStream_t stream) {
    const float* x     = (const float*)d_in[0];
    const int*   ei    = (const int*)d_in[1];
    const int*   batch = (const int*)d_in[2];
    const float* W1    = (const float*)d_in[3];
    const float* b1    = (const float*)d_in[4];
    const float* W2    = (const float*)d_in[5];
    const float* b2    = (const float*)d_in[6];
    const float* Wl    = (const float*)d_in[7];
    const float* bl    = (const float*)d_in[8];
    float*       out   = (float*)d_out;

    char* p = (char*)d_ws;
    auto alloc = [&](size_t bytes) {
        char* r = p;
        p += (bytes + 255) & ~(size_t)255;
        return r;
    };
    int*            deg    = (int*)            alloc((size_t)N_NODES * 4);
    int*            cur    = (int*)            alloc((size_t)N_NODES * 4);
    int*            rowptr = (int*)            alloc((size_t)(N_NODES + 1) * 4);
    int*            bsum   = (int*)            alloc((size_t)SCAN_NB * 4);
    float*          dinv   = (float*)          alloc((size_t)N_NODES * 4);
    int*            colsrc = (int*)            alloc((size_t)N_EDGES * 4);
    unsigned short* hA     = (unsigned short*) alloc((size_t)N_NODES * H_DIM * 2);
    unsigned short* hB     = (unsigned short*) alloc((size_t)N_NODES * H_DIM * 2);
    unsigned short* Wp1    = (unsigned short*) alloc((size_t)1024 * 8 * 2);
    unsigned short* Wp2    = (unsigned short*) alloc((size_t)512 * 8 * 2);

    hipMemsetAsync(deg, 0, (size_t)N_NODES * 4, stream);

    int eb  = (N_EDGES + 255) / 256;
    int nb  = (N_NODES + 255) / 256;
    int nb4 = (N_NODES + 3) / 4;
    int gb  = (N_NODES + 63) / 64;

    count_deg   <<<eb, 256, 0, stream>>>(ei, deg);
    compute_dinv<<<nb, 256, 0, stream>>>(deg, dinv);
    block_sums  <<<SCAN_NB, 256, 0, stream>>>(deg, bsum);
    scan_bsums  <<<1, 512, 0, stream>>>(bsum);
    write_rowptr<<<SCAN_NB, 256, 0, stream>>>(deg, bsum, rowptr, cur);
    fill_csr    <<<eb, 256, 0, stream>>>(ei, rowptr, cur, colsrc);
    pack_weights<<<6, 256, 0, stream>>>(W1, W2, Wp1, Wp2);

    gemm_mfma<F_IN, false><<<gb, 256, 0, stream>>>(x, Wp1, dinv, hA);     // h1' = (x@W1)*dinv
    agg_fast<1><<<nb4, 256, 0, stream>>>(hA, dinv, rowptr, colsrc, b1, hB); // z1 = relu(agg+b1)
    gemm_mfma<H_DIM, true><<<gb, 256, 0, stream>>>(hB, Wp2, dinv, hA);    // h2' = (z1@W2)*dinv
    agg_fast<0><<<nb4, 256, 0, stream>>>(hA, dinv, rowptr, colsrc, b2, hB); // z2 = agg+b2
    pool_head<<<N_GRAPH, 256, 0, stream>>>(hB, batch, Wl, bl, out);
}

// Round 7
// 240.236 us; speedup vs baseline: 3.4438x; 1.1401x over previous
//
#include <hip/hip_runtime.h>

#define N_NODES 100000
#define N_EDGES 1250000
#define F_IN    128
#define H_DIM   64
#define N_CLS   10
#define N_GRAPH 1000

#define SCAN_NB ((N_NODES + 255) / 256)   // 391 (also = number of node buckets)
#define NBKT    SCAN_NB
#define BIN_T     32
#define BIN_CHUNK (256 * BIN_T)           // 8192 edges per block
#define BIN_NB    ((N_EDGES + BIN_CHUNK - 1) / BIN_CHUNK)

typedef __attribute__((ext_vector_type(8))) short bf16x8;
typedef __attribute__((ext_vector_type(4))) float f32x4;

__device__ __forceinline__ unsigned short f2bf(float f) {  // RNE fp32 -> bf16
    unsigned int u = __builtin_bit_cast(unsigned int, f);
    u += 0x7FFFu + ((u >> 16) & 1u);
    return (unsigned short)(u >> 16);
}
__device__ __forceinline__ float bf2f(unsigned short h) {
    unsigned int u = (unsigned int)h << 16;
    return __builtin_bit_cast(float, u);
}
__device__ __forceinline__ float bflo(unsigned int g) { return bf2f((unsigned short)(g & 0xFFFFu)); }
__device__ __forceinline__ float bfhi(unsigned int g) { return bf2f((unsigned short)(g >> 16)); }

// ---------------- CSR build ----------------

__global__ void count_deg(const int* __restrict__ ei, int* __restrict__ deg) {
    int e = blockIdx.x * blockDim.x + threadIdx.x;
    if (e < N_EDGES) {
        int dst = ei[N_EDGES + e];
        atomicAdd(&deg[dst], 1);
    }
}

__global__ void compute_dinv(const int* __restrict__ deg, float* __restrict__ dinv) {
    int i = blockIdx.x * blockDim.x + threadIdx.x;
    if (i < N_NODES) dinv[i] = rsqrtf((float)deg[i] + 1.0f);  // +1 self-loop
}

__global__ void block_sums(const int* __restrict__ deg, int* __restrict__ bsum) {
    int i = blockIdx.x * 256 + threadIdx.x;
    int v = (i < N_NODES) ? deg[i] : 0;
    for (int off = 32; off; off >>= 1) v += __shfl_xor(v, off);
    __shared__ int ws[4];
    if ((threadIdx.x & 63) == 0) ws[threadIdx.x >> 6] = v;
    __syncthreads();
    if (threadIdx.x == 0) bsum[blockIdx.x] = ws[0] + ws[1] + ws[2] + ws[3];
}

__global__ void scan_bsums(int* __restrict__ bsum) {
    __shared__ int s[512];
    int t = threadIdx.x;
    int v = (t < SCAN_NB) ? bsum[t] : 0;
    s[t] = v;
    __syncthreads();
    for (int off = 1; off < 512; off <<= 1) {
        int u = (t >= off) ? s[t - off] : 0;
        __syncthreads();
        s[t] += u;
        __syncthreads();
    }
    if (t < SCAN_NB) bsum[t] = s[t] - v;  // exclusive prefix
}

__global__ void write_rowptr(const int* __restrict__ deg, const int* __restrict__ bsum,
                             int* __restrict__ rowptr, int* __restrict__ btail) {
    int i    = blockIdx.x * 256 + threadIdx.x;
    int lane = threadIdx.x & 63;
    int wid  = threadIdx.x >> 6;
    int v    = (i < N_NODES) ? deg[i] : 0;
    int inc  = v;
    for (int off = 1; off < 64; off <<= 1) {
        int u = __shfl_up(inc, off);
        if (lane >= off) inc += u;
    }
    __shared__ int ws[4];
    if (lane == 63) ws[wid] = inc;
    __syncthreads();
    int woff = 0;
    for (int w = 0; w < wid; ++w) woff += ws[w];
    if (i < N_NODES) rowptr[i] = bsum[blockIdx.x] + woff + inc - v;
    if (threadIdx.x == 0) btail[blockIdx.x] = bsum[blockIdx.x];  // bucket append head
    if (i == 0) rowptr[N_NODES] = N_EDGES;
}

// Pass 1: block-aggregated binning of edges by dst bucket (dst>>8).
// Entry: src (17b) | local-dst (8b) << 17. Bucket b's region in `bins` is
// [rowptr[b*256], rowptr[(b+1)*256]) -- same offsets as colsrc.
__global__ void bin_edges(const int* __restrict__ ei, int* __restrict__ btail,
                          unsigned int* __restrict__ bins) {
    __shared__ int hist[NBKT];
    __shared__ int base[NBKT];
    int tid = threadIdx.x;
    for (int b = tid; b < NBKT; b += 256) hist[b] = 0;
    __syncthreads();
    int e0 = blockIdx.x * BIN_CHUNK;
    unsigned short rank[BIN_T];
#pragma unroll
    for (int t = 0; t < BIN_T; ++t) {
        int e = e0 + t * 256 + tid;
        int r = 0;
        if (e < N_EDGES) {
            int b = ei[N_EDGES + e] >> 8;
            r = atomicAdd(&hist[b], 1);
        }
        rank[t] = (unsigned short)r;
    }
    __syncthreads();
    for (int b = tid; b < NBKT; b += 256) {
        int c = hist[b];
        base[b] = c ? atomicAdd(&btail[b], c) : 0;
    }
    __syncthreads();
#pragma unroll
    for (int t = 0; t < BIN_T; ++t) {
        int e = e0 + t * 256 + tid;
        if (e < N_EDGES) {
            int src = ei[e];
            int dst = ei[N_EDGES + e];
            int b = dst >> 8;
            bins[base[b] + (int)rank[t]] = (unsigned int)src | ((unsigned int)(dst & 255) << 17);
        }
    }
}

// Pass 2: one block per bucket; dense L2-resident scatter into colsrc.
__global__ void scatter_csr(const unsigned int* __restrict__ bins, const int* __restrict__ rowptr,
                            int* __restrict__ colsrc) {
    __shared__ int rp[257];
    __shared__ int cur[256];
    int bkt  = blockIdx.x;
    int base = bkt << 8;
    int tid  = threadIdx.x;
    int nn   = N_NODES - base; if (nn > 256) nn = 256;
    for (int i = tid; i <= nn; i += 256) rp[i] = rowptr[base + i];
    if (tid < nn) cur[tid] = 0;
    __syncthreads();
    int pbeg = rp[0], pend = rp[nn];
    for (int p = pbeg + tid; p < pend; p += 256) {
        unsigned int pk = bins[p];
        int src = (int)(pk & 0x1FFFFu);
        int ld  = (int)(pk >> 17);
        int loc = atomicAdd(&cur[ld], 1);
        colsrc[rp[ld] + loc] = src;
    }
}

// ---------------- weight packing (fp32 -> bf16 MFMA B-fragment order) ----------------

__global__ void pack_weights(const float* __restrict__ W1, const float* __restrict__ W2,
                             unsigned short* __restrict__ Wp1, unsigned short* __restrict__ Wp2) {
    int idx = blockIdx.x * 256 + threadIdx.x;   // 0..1535
    if (idx < 1024) {                           // W1: K=128 -> 4 chunks x 4 tiles
        int l = idx & 63, tc = idx >> 6;
        int c = tc & 3, t = tc >> 2;
        for (int j = 0; j < 8; ++j)
            Wp1[idx * 8 + j] = f2bf(W1[(c * 32 + (l >> 4) * 8 + j) * H_DIM + t * 16 + (l & 15)]);
    } else if (idx < 1536) {                    // W2: K=64 -> 2 chunks x 4 tiles
        int i2 = idx - 1024;
        int l = i2 & 63, tc = i2 >> 6;
        int c = tc & 1, t = tc >> 1;
        for (int j = 0; j < 8; ++j)
            Wp2[i2 * 8 + j] = f2bf(W2[(c * 32 + (l >> 4) * 8 + j) * H_DIM + t * 16 + (l & 15)]);
    }
}

// ---------------- MFMA GEMM:  Y[row][col] = (A[row][:] @ W[:,col]) * dinv[row]  (bf16 out) ----

template<int K, bool ABF>
__global__ void gemm_mfma(const void* __restrict__ Ap, const unsigned short* __restrict__ Wp,
                          const float* __restrict__ dinv, unsigned short* __restrict__ Y) {
    int lane = threadIdx.x & 63;
    int wave = threadIdx.x >> 6;
    int l16 = lane & 15, lhi = lane >> 4;
    int row0 = blockIdx.x * 64 + wave * 16;
    int arow = row0 + l16;
    bool aok = (arow < N_NODES);

    f32x4 acc[4];
#pragma unroll
    for (int t = 0; t < 4; ++t) acc[t] = (f32x4){0.f, 0.f, 0.f, 0.f};

#pragma unroll
    for (int c = 0; c < K / 32; ++c) {
        bf16x8 a;
        if (ABF) {
            if (aok) a = *(const bf16x8*)((const unsigned short*)Ap + (size_t)arow * K + c * 32 + lhi * 8);
            else     a = (bf16x8){0, 0, 0, 0, 0, 0, 0, 0};
        } else {
            if (aok) {
                const float* Af = (const float*)Ap + (size_t)arow * K + c * 32 + lhi * 8;
                float4 f0 = *(const float4*)(Af);
                float4 f1 = *(const float4*)(Af + 4);
                a = (bf16x8){(short)f2bf(f0.x), (short)f2bf(f0.y), (short)f2bf(f0.z), (short)f2bf(f0.w),
                             (short)f2bf(f1.x), (short)f2bf(f1.y), (short)f2bf(f1.z), (short)f2bf(f1.w)};
            } else a = (bf16x8){0, 0, 0, 0, 0, 0, 0, 0};
        }
#pragma unroll
        for (int t = 0; t < 4; ++t) {
            bf16x8 b = *(const bf16x8*)(Wp + ((size_t)(t * (K / 32) + c) * 64 + lane) * 8);
            acc[t] = __builtin_amdgcn_mfma_f32_16x16x32_bf16(a, b, acc[t], 0, 0, 0);
        }
    }

#pragma unroll
    for (int r = 0; r < 4; ++r) {
        int row = row0 + lhi * 4 + r;
        if (row < N_NODES) {
            float dv = dinv[row];
#pragma unroll
            for (int t = 0; t < 4; ++t)
                Y[(size_t)row * H_DIM + t * 16 + l16] = f2bf(acc[t][r] * dv);
        }
    }
}

// ---------------- aggregation (gather, latency-optimized) ----------------

template<int RELU>
__global__ void agg_fast(const unsigned short* __restrict__ Hb, const float* __restrict__ dinv,
                         const int* __restrict__ rowptr, const int* __restrict__ colsrc,
                         const float* __restrict__ bias, unsigned short* __restrict__ Z) {
    int tid  = threadIdx.x;
    int node = blockIdx.x * 4 + (tid >> 6);
    int lane = tid & 63;
    if (node >= N_NODES) return;
    int half = lane >> 5;           // which of the 2 concurrent edges
    int fp   = lane & 31;           // feature-pair index (features 2fp, 2fp+1)

    const unsigned int* H32 = (const unsigned int*)Hb;

    float ax = 0.f, ay = 0.f;
    if (half == 0) {                // self term once
        unsigned int g = H32[(size_t)node * 32 + fp];
        ax = bflo(g); ay = bfhi(g);
    }

    int beg = rowptr[node], end = rowptr[node + 1];
    int p = beg;
    for (; p + 8 <= end; p += 8) {
        int s0 = colsrc[p + half];
        int s1 = colsrc[p + 2 + half];
        int s2 = colsrc[p + 4 + half];
        int s3 = colsrc[p + 6 + half];
        unsigned int g0 = H32[(size_t)s0 * 32 + fp];
        unsigned int g1 = H32[(size_t)s1 * 32 + fp];
        unsigned int g2 = H32[(size_t)s2 * 32 + fp];
        unsigned int g3 = H32[(size_t)s3 * 32 + fp];
        ax += bflo(g0) + bflo(g1) + bflo(g2) + bflo(g3);
        ay += bfhi(g0) + bfhi(g1) + bfhi(g2) + bfhi(g3);
    }
    {   // masked tail
        int e0 = p + half;
        int s0 = (e0     < end) ? colsrc[e0]     : -1;
        int s1 = (e0 + 2 < end) ? colsrc[e0 + 2] : -1;
        int s2 = (e0 + 4 < end) ? colsrc[e0 + 4] : -1;
        int s3 = (e0 + 6 < end) ? colsrc[e0 + 6] : -1;
        unsigned int g0 = H32[(size_t)(s0 < 0 ? 0 : s0) * 32 + fp];
        unsigned int g1 = H32[(size_t)(s1 < 0 ? 0 : s1) * 32 + fp];
        unsigned int g2 = H32[(size_t)(s2 < 0 ? 0 : s2) * 32 + fp];
        unsigned int g3 = H32[(size_t)(s3 < 0 ? 0 : s3) * 32 + fp];
        if (s0 >= 0) { ax += bflo(g0); ay += bfhi(g0); }
        if (s1 >= 0) { ax += bflo(g1); ay += bfhi(g1); }
        if (s2 >= 0) { ax += bflo(g2); ay += bfhi(g2); }
        if (s3 >= 0) { ax += bflo(g3); ay += bfhi(g3); }
    }

    ax += __shfl_xor(ax, 32);
    ay += __shfl_xor(ay, 32);

    if (half == 0) {
        float dv = dinv[node];
        float2 bb = *(const float2*)(bias + 2 * fp);
        float vx = ax * dv + bb.x;
        float vy = ay * dv + bb.y;
        if (RELU) { vx = fmaxf(vx, 0.f); vy = fmaxf(vy, 0.f); }
        unsigned int pk = (unsigned int)f2bf(vx) | ((unsigned int)f2bf(vy) << 16);
        *(((unsigned int*)Z) + (size_t)node * 32 + fp) = pk;
    }
}

// ---------------- fused pooling + head (batch sorted -> contiguous segments) ----------------

__global__ void pool_head(const unsigned short* __restrict__ Hb, const int* __restrict__ batch,
                          const float* __restrict__ Wl, const float* __restrict__ bl,
                          float* __restrict__ out) {
    int g    = blockIdx.x;
    int tid  = threadIdx.x;   // 0..255
    int rg   = tid >> 6;
    int lane = tid & 63;

    auto lb = [&](int key) {
        int lo = 0, hi = N_NODES;
        while (lo < hi) {
            int mid = (lo + hi) >> 1;
            if (batch[mid] < key) lo = mid + 1; else hi = mid;
        }
        return lo;
    };
    int beg = lb(g);
    int end = lb(g + 1);

    float acc = 0.f;
    for (int i = beg + rg; i < end; i += 4)
        acc += bf2f(Hb[(size_t)i * H_DIM + lane]);

    __shared__ float s[4][H_DIM];
    s[rg][lane] = acc;
    __syncthreads();

    if (rg == 0) {
        float p = s[0][lane] + s[1][lane] + s[2][lane] + s[3][lane];
        p *= 1.0f / fmaxf((float)(end - beg), 1.0f);

        __shared__ float logits[N_CLS];
        for (int c = 0; c < N_CLS; ++c) {
            float v = p * Wl[lane * N_CLS + c];
            for (int off = 32; off; off >>= 1) v += __shfl_xor(v, off);
            if (lane == 0) logits[c] = v + bl[c];
        }
        if (lane == 0) {
            float m = logits[0];
            for (int c = 1; c < N_CLS; ++c) m = fmaxf(m, logits[c]);
            float sum = 0.f;
            for (int c = 0; c < N_CLS; ++c) sum += expf(logits[c] - m);
            float ls = logf(sum);
            for (int c = 0; c < N_CLS; ++c) out[g * N_CLS + c] = logits[c] - m - ls;
        }
    }
}

// ---------------- launch ----------------

extern "C" void kernel_launch(void* const* d_in, const int* in_sizes, int n_in,
                              void* d_out, int out_size, void* d_ws, size_t ws_size,
                              hipStream_t stream) {
    const float* x     = (const float*)d_in[0];
    const int*   ei    = (const int*)d_in[1];
    const int*   batch = (const int*)d_in[2];
    const float* W1    = (const float*)d_in[3];
    const float* b1    = (const float*)d_in[4];
    const float* W2    = (const float*)d_in[5];
    const float* b2    = (const float*)d_in[6];
    const float* Wl    = (const float*)d_in[7];
    const float* bl    = (const float*)d_in[8];
    float*       out   = (float*)d_out;

    char* p = (char*)d_ws;
    auto alloc = [&](size_t bytes) {
        char* r = p;
        p += (bytes + 255) & ~(size_t)255;
        return r;
    };
    int*            deg    = (int*)            alloc((size_t)N_NODES * 4);
    int*            rowptr = (int*)            alloc((size_t)(N_NODES + 1) * 4);
    int*            bsum   = (int*)            alloc((size_t)SCAN_NB * 4);
    int*            btail  = (int*)            alloc((size_t)NBKT * 4);
    float*          dinv   = (float*)          alloc((size_t)N_NODES * 4);
    int*            colsrc = (int*)            alloc((size_t)N_EDGES * 4);
    unsigned int*   bins   = (unsigned int*)   alloc((size_t)N_EDGES * 4);
    unsigned short* hA     = (unsigned short*) alloc((size_t)N_NODES * H_DIM * 2);
    unsigned short* hB     = (unsigned short*) alloc((size_t)N_NODES * H_DIM * 2);
    unsigned short* Wp1    = (unsigned short*) alloc((size_t)1024 * 8 * 2);
    unsigned short* Wp2    = (unsigned short*) alloc((size_t)512 * 8 * 2);

    hipMemsetAsync(deg, 0, (size_t)N_NODES * 4, stream);

    int eb  = (N_EDGES + 255) / 256;
    int nb  = (N_NODES + 255) / 256;
    int nb4 = (N_NODES + 3) / 4;
    int gb  = (N_NODES + 63) / 64;

    count_deg   <<<eb, 256, 0, stream>>>(ei, deg);
    compute_dinv<<<nb, 256, 0, stream>>>(deg, dinv);
    block_sums  <<<SCAN_NB, 256, 0, stream>>>(deg, bsum);
    scan_bsums  <<<1, 512, 0, stream>>>(bsum);
    write_rowptr<<<SCAN_NB, 256, 0, stream>>>(deg, bsum, rowptr, btail);
    bin_edges   <<<BIN_NB, 256, 0, stream>>>(ei, btail, bins);
    scatter_csr <<<NBKT, 256, 0, stream>>>(bins, rowptr, colsrc);
    pack_weights<<<6, 256, 0, stream>>>(W1, W2, Wp1, Wp2);

    gemm_mfma<F_IN, false><<<gb, 256, 0, stream>>>(x, Wp1, dinv, hA);       // h1' = (x@W1)*dinv
    agg_fast<1><<<nb4, 256, 0, stream>>>(hA, dinv, rowptr, colsrc, b1, hB); // z1 = relu(agg+b1)
    gemm_mfma<H_DIM, true><<<gb, 256, 0, stream>>>(hB, Wp2, dinv, hA);      // h2' = (z1@W2)*dinv
    agg_fast<0><<<nb4, 256, 0, stream>>>(hA, dinv, rowptr, colsrc, b2, hB); // z2 = agg+b2
    pool_head<<<N_GRAPH, 256, 0, stream>>>(hB, batch, Wl, bl, out);
}

// Round 8
// 195.386 us; speedup vs baseline: 4.2343x; 1.2295x over previous
//
#include <hip/hip_runtime.h>

#define N_NODES 100000
#define N_EDGES 1250000
#define F_IN    128
#define H_DIM   64
#define N_CLS   10
#define N_GRAPH 1000

#define NBKT      ((N_NODES + 255) / 256)   // 391 dst-buckets of 256 nodes
#define BIN_T     32
#define BIN_CHUNK (256 * BIN_T)             // 8192 edges per block
#define BIN_NB    ((N_EDGES + BIN_CHUNK - 1) / BIN_CHUNK)

typedef __attribute__((ext_vector_type(8))) short bf16x8;
typedef __attribute__((ext_vector_type(4))) float f32x4;

__device__ __forceinline__ unsigned short f2bf(float f) {  // RNE fp32 -> bf16
    unsigned int u = __builtin_bit_cast(unsigned int, f);
    u += 0x7FFFu + ((u >> 16) & 1u);
    return (unsigned short)(u >> 16);
}
__device__ __forceinline__ float bf2f(unsigned short h) {
    unsigned int u = (unsigned int)h << 16;
    return __builtin_bit_cast(float, u);
}
__device__ __forceinline__ float bflo(unsigned int g) { return bf2f((unsigned short)(g & 0xFFFFu)); }
__device__ __forceinline__ float bfhi(unsigned int g) { return bf2f((unsigned short)(g >> 16)); }

// ---------------- CSR build (bucketed, no per-node global atomics) ----------------

// Pass 0: per-bucket edge counts (LDS-aggregated; global atomics only on 391 addrs)
__global__ void bkt_count(const int* __restrict__ ei, int* __restrict__ bktcnt) {
    __shared__ int hist[NBKT];
    int tid = threadIdx.x;
    for (int b = tid; b < NBKT; b += 256) hist[b] = 0;
    __syncthreads();
    int e0 = blockIdx.x * BIN_CHUNK;
#pragma unroll
    for (int t = 0; t < BIN_T; ++t) {
        int e = e0 + t * 256 + tid;
        if (e < N_EDGES) atomicAdd(&hist[ei[N_EDGES + e] >> 8], 1);
    }
    __syncthreads();
    for (int b = tid; b < NBKT; b += 256)
        if (hist[b]) atomicAdd(&bktcnt[b], hist[b]);
}

// Pass 0b: exclusive scan of 391 bucket counts -> bktptr; seed btail
__global__ void scan_bkt(const int* __restrict__ bktcnt, int* __restrict__ bktptr,
                         int* __restrict__ btail) {
    __shared__ int s[512];
    int t = threadIdx.x;
    int v = (t < NBKT) ? bktcnt[t] : 0;
    s[t] = v;
    __syncthreads();
    for (int off = 1; off < 512; off <<= 1) {
        int u = (t >= off) ? s[t - off] : 0;
        __syncthreads();
        s[t] += u;
        __syncthreads();
    }
    if (t < NBKT) { int ex = s[t] - v; bktptr[t] = ex; btail[t] = ex; }
    if (t == 0) bktptr[NBKT] = N_EDGES;
}

// Pass 1: block-aggregated binning of edges by dst bucket (dst>>8).
// Entry: src (17b) | local-dst (8b) << 17. Bucket b's region in `bins` is
// [bktptr[b], bktptr[b+1]).
__global__ void bin_edges(const int* __restrict__ ei, int* __restrict__ btail,
                          unsigned int* __restrict__ bins) {
    __shared__ int hist[NBKT];
    __shared__ int base[NBKT];
    int tid = threadIdx.x;
    for (int b = tid; b < NBKT; b += 256) hist[b] = 0;
    __syncthreads();
    int e0 = blockIdx.x * BIN_CHUNK;
    unsigned short rank[BIN_T];
#pragma unroll
    for (int t = 0; t < BIN_T; ++t) {
        int e = e0 + t * 256 + tid;
        int r = 0;
        if (e < N_EDGES) {
            int b = ei[N_EDGES + e] >> 8;
            r = atomicAdd(&hist[b], 1);
        }
        rank[t] = (unsigned short)r;
    }
    __syncthreads();
    for (int b = tid; b < NBKT; b += 256) {
        int c = hist[b];
        base[b] = c ? atomicAdd(&btail[b], c) : 0;
    }
    __syncthreads();
#pragma unroll
    for (int t = 0; t < BIN_T; ++t) {
        int e = e0 + t * 256 + tid;
        if (e < N_EDGES) {
            int src = ei[e];
            int dst = ei[N_EDGES + e];
            int b = dst >> 8;
            bins[base[b] + (int)rank[t]] = (unsigned int)src | ((unsigned int)(dst & 255) << 17);
        }
    }
}

// Pass 2: one block per bucket -- per-node counts (LDS), block scan -> rowptr +
// dinv, then dense L2-resident scatter into colsrc. Replaces count_deg /
// compute_dinv / block_sums / scan_bsums / write_rowptr / scatter_csr.
__global__ void bucket_build(const unsigned int* __restrict__ bins, const int* __restrict__ bktptr,
                             int* __restrict__ rowptr, float* __restrict__ dinv,
                             int* __restrict__ colsrc) {
    __shared__ int cnt[256];
    __shared__ int pfx[256];
    __shared__ int cur[256];
    __shared__ int ws[4];
    int bkt  = blockIdx.x;
    int base = bkt << 8;
    int tid  = threadIdx.x;
    int nn   = N_NODES - base; if (nn > 256) nn = 256;
    int pbeg = bktptr[bkt], pend = bktptr[bkt + 1];

    cnt[tid] = 0; cur[tid] = 0;
    __syncthreads();
    for (int p = pbeg + tid; p < pend; p += 256)
        atomicAdd(&cnt[bins[p] >> 17], 1);
    __syncthreads();

    int lane = tid & 63, wid = tid >> 6;
    int v   = cnt[tid];
    int inc = v;
    for (int off = 1; off < 64; off <<= 1) {
        int u = __shfl_up(inc, off);
        if (lane >= off) inc += u;
    }
    if (lane == 63) ws[wid] = inc;
    __syncthreads();
    int woff = 0;
    for (int w = 0; w < wid; ++w) woff += ws[w];
    pfx[tid] = woff + inc - v;   // exclusive prefix within bucket
    __syncthreads();

    if (tid < nn) {
        rowptr[base + tid] = pbeg + pfx[tid];
        dinv[base + tid]   = rsqrtf((float)v + 1.0f);   // +1 self-loop
    }
    if (bkt == NBKT - 1 && tid == 0) rowptr[N_NODES] = N_EDGES;

    for (int p = pbeg + tid; p < pend; p += 256) {
        unsigned int pk = bins[p];
        int ld  = (int)(pk >> 17);
        int loc = atomicAdd(&cur[ld], 1);
        colsrc[pbeg + pfx[ld] + loc] = (int)(pk & 0x1FFFFu);
    }
}

// ---------------- weight packing (fp32 -> bf16 MFMA B-fragment order) ----------------

__global__ void pack_weights(const float* __restrict__ W1, const float* __restrict__ W2,
                             unsigned short* __restrict__ Wp1, unsigned short* __restrict__ Wp2) {
    int idx = blockIdx.x * 256 + threadIdx.x;   // 0..1535
    if (idx < 1024) {                           // W1: K=128 -> 4 chunks x 4 tiles
        int l = idx & 63, tc = idx >> 6;
        int c = tc & 3, t = tc >> 2;
        for (int j = 0; j < 8; ++j)
            Wp1[idx * 8 + j] = f2bf(W1[(c * 32 + (l >> 4) * 8 + j) * H_DIM + t * 16 + (l & 15)]);
    } else if (idx < 1536) {                    // W2: K=64 -> 2 chunks x 4 tiles
        int i2 = idx - 1024;
        int l = i2 & 63, tc = i2 >> 6;
        int c = tc & 1, t = tc >> 1;
        for (int j = 0; j < 8; ++j)
            Wp2[i2 * 8 + j] = f2bf(W2[(c * 32 + (l >> 4) * 8 + j) * H_DIM + t * 16 + (l & 15)]);
    }
}

// ---------------- MFMA GEMM:  Y[row][col] = (A[row][:] @ W[:,col]) * dinv[row]  (bf16 out) ----

template<int K, bool ABF>
__global__ void gemm_mfma(const void* __restrict__ Ap, const unsigned short* __restrict__ Wp,
                          const float* __restrict__ dinv, unsigned short* __restrict__ Y) {
    int lane = threadIdx.x & 63;
    int wave = threadIdx.x >> 6;
    int l16 = lane & 15, lhi = lane >> 4;
    int row0 = blockIdx.x * 64 + wave * 16;
    int arow = row0 + l16;
    bool aok = (arow < N_NODES);

    f32x4 acc[4];
#pragma unroll
    for (int t = 0; t < 4; ++t) acc[t] = (f32x4){0.f, 0.f, 0.f, 0.f};

#pragma unroll
    for (int c = 0; c < K / 32; ++c) {
        bf16x8 a;
        if (ABF) {
            if (aok) a = *(const bf16x8*)((const unsigned short*)Ap + (size_t)arow * K + c * 32 + lhi * 8);
            else     a = (bf16x8){0, 0, 0, 0, 0, 0, 0, 0};
        } else {
            if (aok) {
                const float* Af = (const float*)Ap + (size_t)arow * K + c * 32 + lhi * 8;
                float4 f0 = *(const float4*)(Af);
                float4 f1 = *(const float4*)(Af + 4);
                a = (bf16x8){(short)f2bf(f0.x), (short)f2bf(f0.y), (short)f2bf(f0.z), (short)f2bf(f0.w),
                             (short)f2bf(f1.x), (short)f2bf(f1.y), (short)f2bf(f1.z), (short)f2bf(f1.w)};
            } else a = (bf16x8){0, 0, 0, 0, 0, 0, 0, 0};
        }
#pragma unroll
        for (int t = 0; t < 4; ++t) {
            bf16x8 b = *(const bf16x8*)(Wp + ((size_t)(t * (K / 32) + c) * 64 + lane) * 8);
            acc[t] = __builtin_amdgcn_mfma_f32_16x16x32_bf16(a, b, acc[t], 0, 0, 0);
        }
    }

#pragma unroll
    for (int r = 0; r < 4; ++r) {
        int row = row0 + lhi * 4 + r;
        if (row < N_NODES) {
            float dv = dinv[row];
#pragma unroll
            for (int t = 0; t < 4; ++t)
                Y[(size_t)row * H_DIM + t * 16 + l16] = f2bf(acc[t][r] * dv);
        }
    }
}

// ---------------- aggregation (gather, latency-optimized) ----------------

template<int RELU>
__global__ void agg_fast(const unsigned short* __restrict__ Hb, const float* __restrict__ dinv,
                         const int* __restrict__ rowptr, const int* __restrict__ colsrc,
                         const float* __restrict__ bias, unsigned short* __restrict__ Z) {
    int tid  = threadIdx.x;
    int node = blockIdx.x * 4 + (tid >> 6);
    int lane = tid & 63;
    if (node >= N_NODES) return;
    int half = lane >> 5;           // which of the 2 concurrent edges
    int fp   = lane & 31;           // feature-pair index (features 2fp, 2fp+1)

    const unsigned int* H32 = (const unsigned int*)Hb;

    float ax = 0.f, ay = 0.f;
    if (half == 0) {                // self term once
        unsigned int g = H32[(size_t)node * 32 + fp];
        ax = bflo(g); ay = bfhi(g);
    }

    int beg = rowptr[node], end = rowptr[node + 1];
    int p = beg;
    for (; p + 8 <= end; p += 8) {
        int s0 = colsrc[p + half];
        int s1 = colsrc[p + 2 + half];
        int s2 = colsrc[p + 4 + half];
        int s3 = colsrc[p + 6 + half];
        unsigned int g0 = H32[(size_t)s0 * 32 + fp];
        unsigned int g1 = H32[(size_t)s1 * 32 + fp];
        unsigned int g2 = H32[(size_t)s2 * 32 + fp];
        unsigned int g3 = H32[(size_t)s3 * 32 + fp];
        ax += bflo(g0) + bflo(g1) + bflo(g2) + bflo(g3);
        ay += bfhi(g0) + bfhi(g1) + bfhi(g2) + bfhi(g3);
    }
    {   // masked tail
        int e0 = p + half;
        int s0 = (e0     < end) ? colsrc[e0]     : -1;
        int s1 = (e0 + 2 < end) ? colsrc[e0 + 2] : -1;
        int s2 = (e0 + 4 < end) ? colsrc[e0 + 4] : -1;
        int s3 = (e0 + 6 < end) ? colsrc[e0 + 6] : -1;
        unsigned int g0 = H32[(size_t)(s0 < 0 ? 0 : s0) * 32 + fp];
        unsigned int g1 = H32[(size_t)(s1 < 0 ? 0 : s1) * 32 + fp];
        unsigned int g2 = H32[(size_t)(s2 < 0 ? 0 : s2) * 32 + fp];
        unsigned int g3 = H32[(size_t)(s3 < 0 ? 0 : s3) * 32 + fp];
        if (s0 >= 0) { ax += bflo(g0); ay += bfhi(g0); }
        if (s1 >= 0) { ax += bflo(g1); ay += bfhi(g1); }
        if (s2 >= 0) { ax += bflo(g2); ay += bfhi(g2); }
        if (s3 >= 0) { ax += bflo(g3); ay += bfhi(g3); }
    }

    ax += __shfl_xor(ax, 32);
    ay += __shfl_xor(ay, 32);

    if (half == 0) {
        float dv = dinv[node];
        float2 bb = *(const float2*)(bias + 2 * fp);
        float vx = ax * dv + bb.x;
        float vy = ay * dv + bb.y;
        if (RELU) { vx = fmaxf(vx, 0.f); vy = fmaxf(vy, 0.f); }
        unsigned int pk = (unsigned int)f2bf(vx) | ((unsigned int)f2bf(vy) << 16);
        *(((unsigned int*)Z) + (size_t)node * 32 + fp) = pk;
    }
}

// ---------------- fused pooling + head (batch sorted -> contiguous segments) ----------------

__global__ void pool_head(const unsigned short* __restrict__ Hb, const int* __restrict__ batch,
                          const float* __restrict__ Wl, const float* __restrict__ bl,
                          float* __restrict__ out) {
    int g    = blockIdx.x;
    int tid  = threadIdx.x;   // 0..255
    int rg   = tid >> 6;
    int lane = tid & 63;

    auto lb = [&](int key) {
        int lo = 0, hi = N_NODES;
        while (lo < hi) {
            int mid = (lo + hi) >> 1;
            if (batch[mid] < key) lo = mid + 1; else hi = mid;
        }
        return lo;
    };
    int beg = lb(g);
    int end = lb(g + 1);

    float acc = 0.f;
    for (int i = beg + rg; i < end; i += 4)
        acc += bf2f(Hb[(size_t)i * H_DIM + lane]);

    __shared__ float s[4][H_DIM];
    s[rg][lane] = acc;
    __syncthreads();

    if (rg == 0) {
        float p = s[0][lane] + s[1][lane] + s[2][lane] + s[3][lane];
        p *= 1.0f / fmaxf((float)(end - beg), 1.0f);

        __shared__ float logits[N_CLS];
        for (int c = 0; c < N_CLS; ++c) {
            float v = p * Wl[lane * N_CLS + c];
            for (int off = 32; off; off >>= 1) v += __shfl_xor(v, off);
            if (lane == 0) logits[c] = v + bl[c];
        }
        if (lane == 0) {
            float m = logits[0];
            for (int c = 1; c < N_CLS; ++c) m = fmaxf(m, logits[c]);
            float sum = 0.f;
            for (int c = 0; c < N_CLS; ++c) sum += expf(logits[c] - m);
            float ls = logf(sum);
            for (int c = 0; c < N_CLS; ++c) out[g * N_CLS + c] = logits[c] - m - ls;
        }
    }
}

// ---------------- launch ----------------

extern "C" void kernel_launch(void* const* d_in, const int* in_sizes, int n_in,
                              void* d_out, int out_size, void* d_ws, size_t ws_size,
                              hipStream_t stream) {
    const float* x     = (const float*)d_in[0];
    const int*   ei    = (const int*)d_in[1];
    const int*   batch = (const int*)d_in[2];
    const float* W1    = (const float*)d_in[3];
    const float* b1    = (const float*)d_in[4];
    const float* W2    = (const float*)d_in[5];
    const float* b2    = (const float*)d_in[6];
    const float* Wl    = (const float*)d_in[7];
    const float* bl    = (const float*)d_in[8];
    float*       out   = (float*)d_out;

    char* p = (char*)d_ws;
    auto alloc = [&](size_t bytes) {
        char* r = p;
        p += (bytes + 255) & ~(size_t)255;
        return r;
    };
    int*            bktcnt = (int*)            alloc((size_t)NBKT * 4);
    int*            bktptr = (int*)            alloc((size_t)(NBKT + 1) * 4);
    int*            btail  = (int*)            alloc((size_t)NBKT * 4);
    int*            rowptr = (int*)            alloc((size_t)(N_NODES + 1) * 4);
    float*          dinv   = (float*)          alloc((size_t)N_NODES * 4);
    int*            colsrc = (int*)            alloc((size_t)N_EDGES * 4);
    unsigned int*   bins   = (unsigned int*)   alloc((size_t)N_EDGES * 4);
    unsigned short* hA     = (unsigned short*) alloc((size_t)N_NODES * H_DIM * 2);
    unsigned short* hB     = (unsigned short*) alloc((size_t)N_NODES * H_DIM * 2);
    unsigned short* Wp1    = (unsigned short*) alloc((size_t)1024 * 8 * 2);
    unsigned short* Wp2    = (unsigned short*) alloc((size_t)512 * 8 * 2);

    hipMemsetAsync(bktcnt, 0, (size_t)NBKT * 4, stream);

    int nb4 = (N_NODES + 3) / 4;
    int gb  = (N_NODES + 63) / 64;

    bkt_count   <<<BIN_NB, 256, 0, stream>>>(ei, bktcnt);
    scan_bkt    <<<1, 512, 0, stream>>>(bktcnt, bktptr, btail);
    bin_edges   <<<BIN_NB, 256, 0, stream>>>(ei, btail, bins);
    bucket_build<<<NBKT, 256, 0, stream>>>(bins, bktptr, rowptr, dinv, colsrc);
    pack_weights<<<6, 256, 0, stream>>>(W1, W2, Wp1, Wp2);

    gemm_mfma<F_IN, false><<<gb, 256, 0, stream>>>(x, Wp1, dinv, hA);       // h1' = (x@W1)*dinv
    agg_fast<1><<<nb4, 256, 0, stream>>>(hA, dinv, rowptr, colsrc, b1, hB); // z1 = relu(agg+b1)
    gemm_mfma<H_DIM, true><<<gb, 256, 0, stream>>>(hB, Wp2, dinv, hA);      // h2' = (z1@W2)*dinv
    agg_fast<0><<<nb4, 256, 0, stream>>>(hA, dinv, rowptr, colsrc, b2, hB); // z2 = agg+b2
    pool_head<<<N_GRAPH, 256, 0, stream>>>(hB, batch, Wl, bl, out);
}

// Round 9
// 188.072 us; speedup vs baseline: 4.3990x; 1.0389x over previous
//
#include <hip/hip_runtime.h>

#define N_NODES 100000
#define N_EDGES 1250000
#define F_IN    128
#define H_DIM   64
#define N_CLS   10
#define N_GRAPH 1000

#define NBKT      ((N_NODES + 255) / 256)   // 391 dst-buckets of 256 nodes
#define BIN_T     32
#define BIN_CHUNK (256 * BIN_T)             // 8192 edges per block
#define BIN_NB    ((N_EDGES + BIN_CHUNK - 1) / BIN_CHUNK)

typedef __attribute__((ext_vector_type(8))) short bf16x8;
typedef __attribute__((ext_vector_type(4))) float f32x4;

__device__ __forceinline__ unsigned short f2bf(float f) {  // RNE fp32 -> bf16
    unsigned int u = __builtin_bit_cast(unsigned int, f);
    u += 0x7FFFu + ((u >> 16) & 1u);
    return (unsigned short)(u >> 16);
}
__device__ __forceinline__ float bf2f(unsigned short h) {
    unsigned int u = (unsigned int)h << 16;
    return __builtin_bit_cast(float, u);
}
__device__ __forceinline__ float bflo(unsigned int g) {
    return __builtin_bit_cast(float, g << 16);
}
__device__ __forceinline__ float bfhi(unsigned int g) {
    return __builtin_bit_cast(float, g & 0xFFFF0000u);
}

// ---------------- CSR build (bucketed, no per-node global atomics) ----------------

__global__ void bkt_count(const int* __restrict__ ei, int* __restrict__ bktcnt) {
    __shared__ int hist[NBKT];
    int tid = threadIdx.x;
    for (int b = tid; b < NBKT; b += 256) hist[b] = 0;
    __syncthreads();
    int e0 = blockIdx.x * BIN_CHUNK;
#pragma unroll
    for (int t = 0; t < BIN_T; ++t) {
        int e = e0 + t * 256 + tid;
        if (e < N_EDGES) atomicAdd(&hist[ei[N_EDGES + e] >> 8], 1);
    }
    __syncthreads();
    for (int b = tid; b < NBKT; b += 256)
        if (hist[b]) atomicAdd(&bktcnt[b], hist[b]);
}

__global__ void scan_bkt(const int* __restrict__ bktcnt, int* __restrict__ bktptr,
                         int* __restrict__ btail) {
    __shared__ int s[512];
    int t = threadIdx.x;
    int v = (t < NBKT) ? bktcnt[t] : 0;
    s[t] = v;
    __syncthreads();
    for (int off = 1; off < 512; off <<= 1) {
        int u = (t >= off) ? s[t - off] : 0;
        __syncthreads();
        s[t] += u;
        __syncthreads();
    }
    if (t < NBKT) { int ex = s[t] - v; bktptr[t] = ex; btail[t] = ex; }
    if (t == 0) bktptr[NBKT] = N_EDGES;
}

__global__ void bin_edges(const int* __restrict__ ei, int* __restrict__ btail,
                          unsigned int* __restrict__ bins) {
    __shared__ int hist[NBKT];
    __shared__ int base[NBKT];
    int tid = threadIdx.x;
    for (int b = tid; b < NBKT; b += 256) hist[b] = 0;
    __syncthreads();
    int e0 = blockIdx.x * BIN_CHUNK;
    unsigned short rank[BIN_T];
#pragma unroll
    for (int t = 0; t < BIN_T; ++t) {
        int e = e0 + t * 256 + tid;
        int r = 0;
        if (e < N_EDGES) {
            int b = ei[N_EDGES + e] >> 8;
            r = atomicAdd(&hist[b], 1);
        }
        rank[t] = (unsigned short)r;
    }
    __syncthreads();
    for (int b = tid; b < NBKT; b += 256) {
        int c = hist[b];
        base[b] = c ? atomicAdd(&btail[b], c) : 0;
    }
    __syncthreads();
#pragma unroll
    for (int t = 0; t < BIN_T; ++t) {
        int e = e0 + t * 256 + tid;
        if (e < N_EDGES) {
            int src = ei[e];
            int dst = ei[N_EDGES + e];
            int b = dst >> 8;
            bins[base[b] + (int)rank[t]] = (unsigned int)src | ((unsigned int)(dst & 255) << 17);
        }
    }
}

__global__ void bucket_build(const unsigned int* __restrict__ bins, const int* __restrict__ bktptr,
                             int* __restrict__ rowptr, float* __restrict__ dinv,
                             int* __restrict__ colsrc) {
    __shared__ int cnt[256];
    __shared__ int pfx[256];
    __shared__ int cur[256];
    __shared__ int ws[4];
    int bkt  = blockIdx.x;
    int base = bkt << 8;
    int tid  = threadIdx.x;
    int nn   = N_NODES - base; if (nn > 256) nn = 256;
    int pbeg = bktptr[bkt], pend = bktptr[bkt + 1];

    cnt[tid] = 0; cur[tid] = 0;
    __syncthreads();
    for (int p = pbeg + tid; p < pend; p += 256)
        atomicAdd(&cnt[bins[p] >> 17], 1);
    __syncthreads();

    int lane = tid & 63, wid = tid >> 6;
    int v   = cnt[tid];
    int inc = v;
    for (int off = 1; off < 64; off <<= 1) {
        int u = __shfl_up(inc, off);
        if (lane >= off) inc += u;
    }
    if (lane == 63) ws[wid] = inc;
    __syncthreads();
    int woff = 0;
    for (int w = 0; w < wid; ++w) woff += ws[w];
    pfx[tid] = woff + inc - v;   // exclusive prefix within bucket
    __syncthreads();

    if (tid < nn) {
        rowptr[base + tid] = pbeg + pfx[tid];
        dinv[base + tid]   = rsqrtf((float)v + 1.0f);   // +1 self-loop
    }
    if (bkt == NBKT - 1 && tid == 0) rowptr[N_NODES] = N_EDGES;

    for (int p = pbeg + tid; p < pend; p += 256) {
        unsigned int pk = bins[p];
        int ld  = (int)(pk >> 17);
        int loc = atomicAdd(&cur[ld], 1);
        colsrc[pbeg + pfx[ld] + loc] = (int)(pk & 0x1FFFFu);
    }
}

// ---------------- weight packing (fp32 -> bf16 MFMA B-fragment order) ----------------

__global__ void pack_weights(const float* __restrict__ W1, const float* __restrict__ W2,
                             unsigned short* __restrict__ Wp1, unsigned short* __restrict__ Wp2) {
    int idx = blockIdx.x * 256 + threadIdx.x;   // 0..1535
    if (idx < 1024) {                           // W1: K=128 -> 4 chunks x 4 tiles
        int l = idx & 63, tc = idx >> 6;
        int c = tc & 3, t = tc >> 2;
        for (int j = 0; j < 8; ++j)
            Wp1[idx * 8 + j] = f2bf(W1[(c * 32 + (l >> 4) * 8 + j) * H_DIM + t * 16 + (l & 15)]);
    } else if (idx < 1536) {                    // W2: K=64 -> 2 chunks x 4 tiles
        int i2 = idx - 1024;
        int l = i2 & 63, tc = i2 >> 6;
        int c = tc & 1, t = tc >> 1;
        for (int j = 0; j < 8; ++j)
            Wp2[i2 * 8 + j] = f2bf(W2[(c * 32 + (l >> 4) * 8 + j) * H_DIM + t * 16 + (l & 15)]);
    }
}

// ---------------- MFMA GEMM:  Y[row][col] = (A[row][:] @ W[:,col]) * dinv[row]  (bf16 out) ----

template<int K, bool ABF>
__global__ void gemm_mfma(const void* __restrict__ Ap, const unsigned short* __restrict__ Wp,
                          const float* __restrict__ dinv, unsigned short* __restrict__ Y) {
    int lane = threadIdx.x & 63;
    int wave = threadIdx.x >> 6;
    int l16 = lane & 15, lhi = lane >> 4;
    int row0 = blockIdx.x * 64 + wave * 16;
    int arow = row0 + l16;
    bool aok = (arow < N_NODES);

    f32x4 acc[4];
#pragma unroll
    for (int t = 0; t < 4; ++t) acc[t] = (f32x4){0.f, 0.f, 0.f, 0.f};

#pragma unroll
    for (int c = 0; c < K / 32; ++c) {
        bf16x8 a;
        if (ABF) {
            if (aok) a = *(const bf16x8*)((const unsigned short*)Ap + (size_t)arow * K + c * 32 + lhi * 8);
            else     a = (bf16x8){0, 0, 0, 0, 0, 0, 0, 0};
        } else {
            if (aok) {
                const float* Af = (const float*)Ap + (size_t)arow * K + c * 32 + lhi * 8;
                float4 f0 = *(const float4*)(Af);
                float4 f1 = *(const float4*)(Af + 4);
                a = (bf16x8){(short)f2bf(f0.x), (short)f2bf(f0.y), (short)f2bf(f0.z), (short)f2bf(f0.w),
                             (short)f2bf(f1.x), (short)f2bf(f1.y), (short)f2bf(f1.z), (short)f2bf(f1.w)};
            } else a = (bf16x8){0, 0, 0, 0, 0, 0, 0, 0};
        }
#pragma unroll
        for (int t = 0; t < 4; ++t) {
            bf16x8 b = *(const bf16x8*)(Wp + ((size_t)(t * (K / 32) + c) * 64 + lane) * 8);
            acc[t] = __builtin_amdgcn_mfma_f32_16x16x32_bf16(a, b, acc[t], 0, 0, 0);
        }
    }

#pragma unroll
    for (int r = 0; r < 4; ++r) {
        int row = row0 + lhi * 4 + r;
        if (row < N_NODES) {
            float dv = dinv[row];
#pragma unroll
            for (int t = 0; t < 4; ++t)
                Y[(size_t)row * H_DIM + t * 16 + l16] = f2bf(acc[t][r] * dv);
        }
    }
}

// ---------------- aggregation (gather, 8B/lane, 4 edges/instr, 16 in flight) --------------
// Layout: 4 bf16 features per lane (uint2), 16 lanes per row; quarter q = lane>>4
// handles edge slot q of each group of 4. Unroll 4 -> 16 edges in flight.
// out[i] = dinv[i]*(sum_{e:dst=i} h'[src] + h'[i]) + b, h' = h*dinv (pre-scaled)

template<int RELU>
__global__ void agg_fast(const unsigned short* __restrict__ Hb, const float* __restrict__ dinv,
                         const int* __restrict__ rowptr, const int* __restrict__ colsrc,
                         const float* __restrict__ bias, unsigned short* __restrict__ Z) {
    int tid  = threadIdx.x;
    int node = blockIdx.x * 4 + (tid >> 6);
    int lane = tid & 63;
    if (node >= N_NODES) return;
    int q  = lane >> 4;           // edge slot 0..3
    int fq = lane & 15;           // feature-quad: features 4fq..4fq+3

    const uint2* H64 = (const uint2*)Hb;   // 8B granules; 16 per row

    float2 a0 = {0.f, 0.f}, a1 = {0.f, 0.f};
    if (q == 0) {                 // self term once
        uint2 g = H64[(size_t)node * 16 + fq];
        a0.x = bflo(g.x); a0.y = bfhi(g.x);
        a1.x = bflo(g.y); a1.y = bfhi(g.y);
    }

    int beg = rowptr[node], end = rowptr[node + 1];
    int p = beg;
    for (; p + 16 <= end; p += 16) {
        int s0 = colsrc[p + q];
        int s1 = colsrc[p + 4 + q];
        int s2 = colsrc[p + 8 + q];
        int s3 = colsrc[p + 12 + q];
        uint2 g0 = H64[(size_t)s0 * 16 + fq];
        uint2 g1 = H64[(size_t)s1 * 16 + fq];
        uint2 g2 = H64[(size_t)s2 * 16 + fq];
        uint2 g3 = H64[(size_t)s3 * 16 + fq];
        a0.x += bflo(g0.x) + bflo(g1.x) + bflo(g2.x) + bflo(g3.x);
        a0.y += bfhi(g0.x) + bfhi(g1.x) + bfhi(g2.x) + bfhi(g3.x);
        a1.x += bflo(g0.y) + bflo(g1.y) + bflo(g2.y) + bflo(g3.y);
        a1.y += bfhi(g0.y) + bfhi(g1.y) + bfhi(g2.y) + bfhi(g3.y);
    }
    {   // masked tail: < 16 edges remain; issue all gathers, predicate the adds
        int e = p + q;
        int s0 = (e      < end) ? colsrc[e]      : -1;
        int s1 = (e + 4  < end) ? colsrc[e + 4]  : -1;
        int s2 = (e + 8  < end) ? colsrc[e + 8]  : -1;
        int s3 = (e + 12 < end) ? colsrc[e + 12] : -1;
        uint2 g0 = H64[(size_t)(s0 < 0 ? 0 : s0) * 16 + fq];
        uint2 g1 = H64[(size_t)(s1 < 0 ? 0 : s1) * 16 + fq];
        uint2 g2 = H64[(size_t)(s2 < 0 ? 0 : s2) * 16 + fq];
        uint2 g3 = H64[(size_t)(s3 < 0 ? 0 : s3) * 16 + fq];
        if (s0 >= 0) { a0.x += bflo(g0.x); a0.y += bfhi(g0.x); a1.x += bflo(g0.y); a1.y += bfhi(g0.y); }
        if (s1 >= 0) { a0.x += bflo(g1.x); a0.y += bfhi(g1.x); a1.x += bflo(g1.y); a1.y += bfhi(g1.y); }
        if (s2 >= 0) { a0.x += bflo(g2.x); a0.y += bfhi(g2.x); a1.x += bflo(g2.y); a1.y += bfhi(g2.y); }
        if (s3 >= 0) { a0.x += bflo(g3.x); a0.y += bfhi(g3.x); a1.x += bflo(g3.y); a1.y += bfhi(g3.y); }
    }

    // reduce across the 4 quarters (same features, different edges)
    a0.x += __shfl_xor(a0.x, 16); a0.y += __shfl_xor(a0.y, 16);
    a1.x += __shfl_xor(a1.x, 16); a1.y += __shfl_xor(a1.y, 16);
    a0.x += __shfl_xor(a0.x, 32); a0.y += __shfl_xor(a0.y, 32);
    a1.x += __shfl_xor(a1.x, 32); a1.y += __shfl_xor(a1.y, 32);

    if (q == 0) {
        float dv = dinv[node];
        float4 bb = *(const float4*)(bias + 4 * fq);
        float v0 = a0.x * dv + bb.x;
        float v1 = a0.y * dv + bb.y;
        float v2 = a1.x * dv + bb.z;
        float v3 = a1.y * dv + bb.w;
        if (RELU) {
            v0 = fmaxf(v0, 0.f); v1 = fmaxf(v1, 0.f);
            v2 = fmaxf(v2, 0.f); v3 = fmaxf(v3, 0.f);
        }
        uint2 pk;
        pk.x = (unsigned int)f2bf(v0) | ((unsigned int)f2bf(v1) << 16);
        pk.y = (unsigned int)f2bf(v2) | ((unsigned int)f2bf(v3) << 16);
        *(((uint2*)Z) + (size_t)node * 16 + fq) = pk;
    }
}

// ---------------- fused pooling + head (batch sorted -> contiguous segments) ----------------

__global__ void pool_head(const unsigned short* __restrict__ Hb, const int* __restrict__ batch,
                          const float* __restrict__ Wl, const float* __restrict__ bl,
                          float* __restrict__ out) {
    int g    = blockIdx.x;
    int tid  = threadIdx.x;   // 0..255
    int rg   = tid >> 6;
    int lane = tid & 63;

    auto lb = [&](int key) {
        int lo = 0, hi = N_NODES;
        while (lo < hi) {
            int mid = (lo + hi) >> 1;
            if (batch[mid] < key) lo = mid + 1; else hi = mid;
        }
        return lo;
    };
    int beg = lb(g);
    int end = lb(g + 1);

    float acc = 0.f;
    for (int i = beg + rg; i < end; i += 4)
        acc += bf2f(Hb[(size_t)i * H_DIM + lane]);

    __shared__ float s[4][H_DIM];
    s[rg][lane] = acc;
    __syncthreads();

    if (rg == 0) {
        float p = s[0][lane] + s[1][lane] + s[2][lane] + s[3][lane];
        p *= 1.0f / fmaxf((float)(end - beg), 1.0f);

        __shared__ float logits[N_CLS];
        for (int c = 0; c < N_CLS; ++c) {
            float v = p * Wl[lane * N_CLS + c];
            for (int off = 32; off; off >>= 1) v += __shfl_xor(v, off);
            if (lane == 0) logits[c] = v + bl[c];
        }
        if (lane == 0) {
            float m = logits[0];
            for (int c = 1; c < N_CLS; ++c) m = fmaxf(m, logits[c]);
            float sum = 0.f;
            for (int c = 0; c < N_CLS; ++c) sum += expf(logits[c] - m);
            float ls = logf(sum);
            for (int c = 0; c < N_CLS; ++c) out[g * N_CLS + c] = logits[c] - m - ls;
        }
    }
}

// ---------------- launch ----------------

extern "C" void kernel_launch(void* const* d_in, const int* in_sizes, int n_in,
                              void* d_out, int out_size, void* d_ws, size_t ws_size,
                              hipStream_t stream) {
    const float* x     = (const float*)d_in[0];
    const int*   ei    = (const int*)d_in[1];
    const int*   batch = (const int*)d_in[2];
    const float* W1    = (const float*)d_in[3];
    const float* b1    = (const float*)d_in[4];
    const float* W2    = (const float*)d_in[5];
    const float* b2    = (const float*)d_in[6];
    const float* Wl    = (const float*)d_in[7];
    const float* bl    = (const float*)d_in[8];
    float*       out   = (float*)d_out;

    char* p = (char*)d_ws;
    auto alloc = [&](size_t bytes) {
        char* r = p;
        p += (bytes + 255) & ~(size_t)255;
        return r;
    };
    int*            bktcnt = (int*)            alloc((size_t)NBKT * 4);
    int*            bktptr = (int*)            alloc((size_t)(NBKT + 1) * 4);
    int*            btail  = (int*)            alloc((size_t)NBKT * 4);
    int*            rowptr = (int*)            alloc((size_t)(N_NODES + 1) * 4);
    float*          dinv   = (float*)          alloc((size_t)N_NODES * 4);
    int*            colsrc = (int*)            alloc((size_t)N_EDGES * 4);
    unsigned int*   bins   = (unsigned int*)   alloc((size_t)N_EDGES * 4);
    unsigned short* hA     = (unsigned short*) alloc((size_t)N_NODES * H_DIM * 2);
    unsigned short* hB     = (unsigned short*) alloc((size_t)N_NODES * H_DIM * 2);
    unsigned short* Wp1    = (unsigned short*) alloc((size_t)1024 * 8 * 2);
    unsigned short* Wp2    = (unsigned short*) alloc((size_t)512 * 8 * 2);

    hipMemsetAsync(bktcnt, 0, (size_t)NBKT * 4, stream);

    int nb4 = (N_NODES + 3) / 4;
    int gb  = (N_NODES + 63) / 64;

    bkt_count   <<<BIN_NB, 256, 0, stream>>>(ei, bktcnt);
    scan_bkt    <<<1, 512, 0, stream>>>(bktcnt, bktptr, btail);
    bin_edges   <<<BIN_NB, 256, 0, stream>>>(ei, btail, bins);
    bucket_build<<<NBKT, 256, 0, stream>>>(bins, bktptr, rowptr, dinv, colsrc);
    pack_weights<<<6, 256, 0, stream>>>(W1, W2, Wp1, Wp2);

    gemm_mfma<F_IN, false><<<gb, 256, 0, stream>>>(x, Wp1, dinv, hA);       // h1' = (x@W1)*dinv
    agg_fast<1><<<nb4, 256, 0, stream>>>(hA, dinv, rowptr, colsrc, b1, hB); // z1 = relu(agg+b1)
    gemm_mfma<H_DIM, true><<<gb, 256, 0, stream>>>(hB, Wp2, dinv, hA);      // h2' = (z1@W2)*dinv
    agg_fast<0><<<nb4, 256, 0, stream>>>(hA, dinv, rowptr, colsrc, b2, hB); // z2 = agg+b2
    pool_head<<<N_GRAPH, 256, 0, stream>>>(hB, batch, Wl, bl, out);
}

// Round 10
// 177.495 us; speedup vs baseline: 4.6612x; 1.0596x over previous
//
#include <hip/hip_runtime.h>
#include <hip/hip_fp8.h>

#define N_NODES 100000
#define N_EDGES 1250000
#define F_IN    128
#define H_DIM   64
#define N_CLS   10
#define N_GRAPH 1000

#define NBKT      ((N_NODES + 255) / 256)   // 391 dst-buckets of 256 nodes
#define BIN_T     16
#define BIN_CHUNK (256 * BIN_T)             // 4096 edges per block
#define BIN_NB    ((N_EDGES + BIN_CHUNK - 1) / BIN_CHUNK)

typedef __attribute__((ext_vector_type(8))) short bf16x8;
typedef __attribute__((ext_vector_type(4))) float f32x4;

__device__ __forceinline__ unsigned short f2bf(float f) {  // RNE fp32 -> bf16
    unsigned int u = __builtin_bit_cast(unsigned int, f);
    u += 0x7FFFu + ((u >> 16) & 1u);
    return (unsigned short)(u >> 16);
}
__device__ __forceinline__ float bf2f(unsigned short h) {
    unsigned int u = (unsigned int)h << 16;
    return __builtin_bit_cast(float, u);
}
__device__ __forceinline__ float bflo(unsigned int g) {
    return __builtin_bit_cast(float, g << 16);
}
__device__ __forceinline__ float bfhi(unsigned int g) {
    return __builtin_bit_cast(float, g & 0xFFFF0000u);
}
__device__ __forceinline__ float fp8tof(unsigned int b) {
    __hip_fp8_e4m3 v; v.__x = (unsigned char)b; return (float)v;
}
__device__ __forceinline__ unsigned char ftofp8(float f) {
    __hip_fp8_e4m3 v(f); return v.__x;
}

// ---------------- CSR build (bucketed, no per-node global atomics) ----------------

__global__ void bkt_count(const int* __restrict__ ei, int* __restrict__ bktcnt) {
    __shared__ int hist[NBKT];
    int tid = threadIdx.x;
    for (int b = tid; b < NBKT; b += 256) hist[b] = 0;
    __syncthreads();
    int e0 = blockIdx.x * BIN_CHUNK;
#pragma unroll
    for (int t = 0; t < BIN_T; ++t) {
        int e = e0 + t * 256 + tid;
        if (e < N_EDGES) atomicAdd(&hist[ei[N_EDGES + e] >> 8], 1);
    }
    __syncthreads();
    for (int b = tid; b < NBKT; b += 256)
        if (hist[b]) atomicAdd(&bktcnt[b], hist[b]);
}

__global__ void scan_bkt(const int* __restrict__ bktcnt, int* __restrict__ bktptr,
                         int* __restrict__ btail) {
    __shared__ int s[512];
    int t = threadIdx.x;
    int v = (t < NBKT) ? bktcnt[t] : 0;
    s[t] = v;
    __syncthreads();
    for (int off = 1; off < 512; off <<= 1) {
        int u = (t >= off) ? s[t - off] : 0;
        __syncthreads();
        s[t] += u;
        __syncthreads();
    }
    if (t < NBKT) { int ex = s[t] - v; bktptr[t] = ex; btail[t] = ex; }
    if (t == 0) bktptr[NBKT] = N_EDGES;
}

__global__ void bin_edges(const int* __restrict__ ei, int* __restrict__ btail,
                          unsigned int* __restrict__ bins) {
    __shared__ int hist[NBKT];
    __shared__ int base[NBKT];
    int tid = threadIdx.x;
    for (int b = tid; b < NBKT; b += 256) hist[b] = 0;
    __syncthreads();
    int e0 = blockIdx.x * BIN_CHUNK;
    unsigned short rank[BIN_T];
#pragma unroll
    for (int t = 0; t < BIN_T; ++t) {
        int e = e0 + t * 256 + tid;
        int r = 0;
        if (e < N_EDGES) {
            int b = ei[N_EDGES + e] >> 8;
            r = atomicAdd(&hist[b], 1);
        }
        rank[t] = (unsigned short)r;
    }
    __syncthreads();
    for (int b = tid; b < NBKT; b += 256) {
        int c = hist[b];
        base[b] = c ? atomicAdd(&btail[b], c) : 0;
    }
    __syncthreads();
#pragma unroll
    for (int t = 0; t < BIN_T; ++t) {
        int e = e0 + t * 256 + tid;
        if (e < N_EDGES) {
            int src = ei[e];
            int dst = ei[N_EDGES + e];
            int b = dst >> 8;
            bins[base[b] + (int)rank[t]] = (unsigned int)src | ((unsigned int)(dst & 255) << 17);
        }
    }
}

__global__ void bucket_build(const unsigned int* __restrict__ bins, const int* __restrict__ bktptr,
                             int* __restrict__ rowptr, float* __restrict__ dinv,
                             int* __restrict__ colsrc) {
    __shared__ int cnt[256];
    __shared__ int pfx[256];
    __shared__ int cur[256];
    __shared__ int ws[4];
    int bkt  = blockIdx.x;
    int base = bkt << 8;
    int tid  = threadIdx.x;
    int nn   = N_NODES - base; if (nn > 256) nn = 256;
    int pbeg = bktptr[bkt], pend = bktptr[bkt + 1];

    cnt[tid] = 0; cur[tid] = 0;
    __syncthreads();
    for (int p = pbeg + tid; p < pend; p += 256)
        atomicAdd(&cnt[bins[p] >> 17], 1);
    __syncthreads();

    int lane = tid & 63, wid = tid >> 6;
    int v   = cnt[tid];
    int inc = v;
    for (int off = 1; off < 64; off <<= 1) {
        int u = __shfl_up(inc, off);
        if (lane >= off) inc += u;
    }
    if (lane == 63) ws[wid] = inc;
    __syncthreads();
    int woff = 0;
    for (int w = 0; w < wid; ++w) woff += ws[w];
    pfx[tid] = woff + inc - v;   // exclusive prefix within bucket
    __syncthreads();

    if (tid < nn) {
        rowptr[base + tid] = pbeg + pfx[tid];
        dinv[base + tid]   = rsqrtf((float)v + 1.0f);   // +1 self-loop
    }
    if (bkt == NBKT - 1 && tid == 0) rowptr[N_NODES] = N_EDGES;

    for (int p = pbeg + tid; p < pend; p += 256) {
        unsigned int pk = bins[p];
        int ld  = (int)(pk >> 17);
        int loc = atomicAdd(&cur[ld], 1);
        colsrc[pbeg + pfx[ld] + loc] = (int)(pk & 0x1FFFFu);
    }
}

// ---------------- weight packing (fp32 -> bf16 MFMA B-fragment order) ----------------

__global__ void pack_weights(const float* __restrict__ W1, const float* __restrict__ W2,
                             unsigned short* __restrict__ Wp1, unsigned short* __restrict__ Wp2) {
    int idx = blockIdx.x * 256 + threadIdx.x;   // 0..1535
    if (idx < 1024) {                           // W1: K=128 -> 4 chunks x 4 tiles
        int l = idx & 63, tc = idx >> 6;
        int c = tc & 3, t = tc >> 2;
        for (int j = 0; j < 8; ++j)
            Wp1[idx * 8 + j] = f2bf(W1[(c * 32 + (l >> 4) * 8 + j) * H_DIM + t * 16 + (l & 15)]);
    } else if (idx < 1536) {                    // W2: K=64 -> 2 chunks x 4 tiles
        int i2 = idx - 1024;
        int l = i2 & 63, tc = i2 >> 6;
        int c = tc & 1, t = tc >> 1;
        for (int j = 0; j < 8; ++j)
            Wp2[i2 * 8 + j] = f2bf(W2[(c * 32 + (l >> 4) * 8 + j) * H_DIM + t * 16 + (l & 15)]);
    }
}

// ---------------- MFMA GEMM:  Y[row][col] = (A[row][:] @ W[:,col]) * dinv[row] ----------------
// OUT8: store fp8 e4m3 (layer-1 intermediate, gather-traffic optimization), else bf16.

template<int K, bool ABF, bool OUT8>
__global__ void gemm_mfma(const void* __restrict__ Ap, const unsigned short* __restrict__ Wp,
                          const float* __restrict__ dinv, void* __restrict__ Y) {
    int lane = threadIdx.x & 63;
    int wave = threadIdx.x >> 6;
    int l16 = lane & 15, lhi = lane >> 4;
    int row0 = blockIdx.x * 64 + wave * 16;
    int arow = row0 + l16;
    bool aok = (arow < N_NODES);

    f32x4 acc[4];
#pragma unroll
    for (int t = 0; t < 4; ++t) acc[t] = (f32x4){0.f, 0.f, 0.f, 0.f};

#pragma unroll
    for (int c = 0; c < K / 32; ++c) {
        bf16x8 a;
        if (ABF) {
            if (aok) a = *(const bf16x8*)((const unsigned short*)Ap + (size_t)arow * K + c * 32 + lhi * 8);
            else     a = (bf16x8){0, 0, 0, 0, 0, 0, 0, 0};
        } else {
            if (aok) {
                const float* Af = (const float*)Ap + (size_t)arow * K + c * 32 + lhi * 8;
                float4 f0 = *(const float4*)(Af);
                float4 f1 = *(const float4*)(Af + 4);
                a = (bf16x8){(short)f2bf(f0.x), (short)f2bf(f0.y), (short)f2bf(f0.z), (short)f2bf(f0.w),
                             (short)f2bf(f1.x), (short)f2bf(f1.y), (short)f2bf(f1.z), (short)f2bf(f1.w)};
            } else a = (bf16x8){0, 0, 0, 0, 0, 0, 0, 0};
        }
#pragma unroll
        for (int t = 0; t < 4; ++t) {
            bf16x8 b = *(const bf16x8*)(Wp + ((size_t)(t * (K / 32) + c) * 64 + lane) * 8);
            acc[t] = __builtin_amdgcn_mfma_f32_16x16x32_bf16(a, b, acc[t], 0, 0, 0);
        }
    }

#pragma unroll
    for (int r = 0; r < 4; ++r) {
        int row = row0 + lhi * 4 + r;
        if (row < N_NODES) {
            float dv = dinv[row];
#pragma unroll
            for (int t = 0; t < 4; ++t) {
                float v = acc[t][r] * dv;
                if (OUT8) ((unsigned char*) Y)[(size_t)row * H_DIM + t * 16 + l16] = ftofp8(v);
                else      ((unsigned short*)Y)[(size_t)row * H_DIM + t * 16 + l16] = f2bf(v);
            }
        }
    }
}

// ---------------- layer-1 aggregation: fp8 gather source (64B/row, 8 edge slots/wave) ------
// out = relu(dinv[i]*(sum h'[src] + h'[i]) + b), h' fp8 pre-scaled by dinv[src]; out bf16.

__global__ void agg_fp8_relu(const unsigned char* __restrict__ Hq, const float* __restrict__ dinv,
                             const int* __restrict__ rowptr, const int* __restrict__ colsrc,
                             const float* __restrict__ bias, unsigned short* __restrict__ Z) {
    int tid  = threadIdx.x;
    int node = blockIdx.x * 4 + (tid >> 6);
    int lane = tid & 63;
    if (node >= N_NODES) return;
    int q  = lane >> 3;          // edge slot 0..7
    int f8 = lane & 7;           // feature-octet: features 8f8..8f8+7

    const uint2* H = (const uint2*)Hq;   // 8B granules; 8 per row

    float a[8];
#pragma unroll
    for (int i = 0; i < 8; ++i) a[i] = 0.f;

    auto acc8 = [&](uint2 g) {
        a[0] += fp8tof(g.x & 255u);  a[1] += fp8tof((g.x >> 8) & 255u);
        a[2] += fp8tof((g.x >> 16) & 255u); a[3] += fp8tof(g.x >> 24);
        a[4] += fp8tof(g.y & 255u);  a[5] += fp8tof((g.y >> 8) & 255u);
        a[6] += fp8tof((g.y >> 16) & 255u); a[7] += fp8tof(g.y >> 24);
    };

    if (q == 0) acc8(H[(size_t)node * 8 + f8]);   // self term once

    int beg = rowptr[node], end = rowptr[node + 1];
    int p = beg;
    for (; p + 16 <= end; p += 16) {
        int s0 = colsrc[p + q];
        int s1 = colsrc[p + 8 + q];
        uint2 g0 = H[(size_t)s0 * 8 + f8];
        uint2 g1 = H[(size_t)s1 * 8 + f8];
        acc8(g0); acc8(g1);
    }
    {   // masked tail: < 16 edges remain
        int e  = p + q;
        int s0 = (e     < end) ? colsrc[e]     : -1;
        int s1 = (e + 8 < end) ? colsrc[e + 8] : -1;
        uint2 g0 = H[(size_t)(s0 < 0 ? 0 : s0) * 8 + f8];
        uint2 g1 = H[(size_t)(s1 < 0 ? 0 : s1) * 8 + f8];
        if (s0 >= 0) acc8(g0);
        if (s1 >= 0) acc8(g1);
    }

    // reduce across the 8 edge slots (same features, different edges)
#pragma unroll
    for (int off = 8; off < 64; off <<= 1) {
#pragma unroll
        for (int i = 0; i < 8; ++i) a[i] += __shfl_xor(a[i], off);
    }

    if (q == 0) {
        float dv = dinv[node];
        float4 b0 = *(const float4*)(bias + 8 * f8);
        float4 b1 = *(const float4*)(bias + 8 * f8 + 4);
        float v[8];
        v[0] = fmaxf(a[0] * dv + b0.x, 0.f); v[1] = fmaxf(a[1] * dv + b0.y, 0.f);
        v[2] = fmaxf(a[2] * dv + b0.z, 0.f); v[3] = fmaxf(a[3] * dv + b0.w, 0.f);
        v[4] = fmaxf(a[4] * dv + b1.x, 0.f); v[5] = fmaxf(a[5] * dv + b1.y, 0.f);
        v[6] = fmaxf(a[6] * dv + b1.z, 0.f); v[7] = fmaxf(a[7] * dv + b1.w, 0.f);
        uint4 pk;
        pk.x = (unsigned int)f2bf(v[0]) | ((unsigned int)f2bf(v[1]) << 16);
        pk.y = (unsigned int)f2bf(v[2]) | ((unsigned int)f2bf(v[3]) << 16);
        pk.z = (unsigned int)f2bf(v[4]) | ((unsigned int)f2bf(v[5]) << 16);
        pk.w = (unsigned int)f2bf(v[6]) | ((unsigned int)f2bf(v[7]) << 16);
        *(((uint4*)Z) + (size_t)node * 8 + f8) = pk;
    }
}

// ---------------- layer-2 aggregation (bf16 gather, 4 edge slots/wave) ----------------

template<int RELU>
__global__ void agg_fast(const unsigned short* __restrict__ Hb, const float* __restrict__ dinv,
                         const int* __restrict__ rowptr, const int* __restrict__ colsrc,
                         const float* __restrict__ bias, unsigned short* __restrict__ Z) {
    int tid  = threadIdx.x;
    int node = blockIdx.x * 4 + (tid >> 6);
    int lane = tid & 63;
    if (node >= N_NODES) return;
    int q  = lane >> 4;           // edge slot 0..3
    int fq = lane & 15;           // feature-quad: features 4fq..4fq+3

    const uint2* H64 = (const uint2*)Hb;   // 8B granules; 16 per row

    float2 a0 = {0.f, 0.f}, a1 = {0.f, 0.f};
    if (q == 0) {                 // self term once
        uint2 g = H64[(size_t)node * 16 + fq];
        a0.x = bflo(g.x); a0.y = bfhi(g.x);
        a1.x = bflo(g.y); a1.y = bfhi(g.y);
    }

    int beg = rowptr[node], end = rowptr[node + 1];
    int p = beg;
    for (; p + 16 <= end; p += 16) {
        int s0 = colsrc[p + q];
        int s1 = colsrc[p + 4 + q];
        int s2 = colsrc[p + 8 + q];
        int s3 = colsrc[p + 12 + q];
        uint2 g0 = H64[(size_t)s0 * 16 + fq];
        uint2 g1 = H64[(size_t)s1 * 16 + fq];
        uint2 g2 = H64[(size_t)s2 * 16 + fq];
        uint2 g3 = H64[(size_t)s3 * 16 + fq];
        a0.x += bflo(g0.x) + bflo(g1.x) + bflo(g2.x) + bflo(g3.x);
        a0.y += bfhi(g0.x) + bfhi(g1.x) + bfhi(g2.x) + bfhi(g3.x);
        a1.x += bflo(g0.y) + bflo(g1.y) + bflo(g2.y) + bflo(g3.y);
        a1.y += bfhi(g0.y) + bfhi(g1.y) + bfhi(g2.y) + bfhi(g3.y);
    }
    {   // masked tail
        int e = p + q;
        int s0 = (e      < end) ? colsrc[e]      : -1;
        int s1 = (e + 4  < end) ? colsrc[e + 4]  : -1;
        int s2 = (e + 8  < end) ? colsrc[e + 8]  : -1;
        int s3 = (e + 12 < end) ? colsrc[e + 12] : -1;
        uint2 g0 = H64[(size_t)(s0 < 0 ? 0 : s0) * 16 + fq];
        uint2 g1 = H64[(size_t)(s1 < 0 ? 0 : s1) * 16 + fq];
        uint2 g2 = H64[(size_t)(s2 < 0 ? 0 : s2) * 16 + fq];
        uint2 g3 = H64[(size_t)(s3 < 0 ? 0 : s3) * 16 + fq];
        if (s0 >= 0) { a0.x += bflo(g0.x); a0.y += bfhi(g0.x); a1.x += bflo(g0.y); a1.y += bfhi(g0.y); }
        if (s1 >= 0) { a0.x += bflo(g1.x); a0.y += bfhi(g1.x); a1.x += bflo(g1.y); a1.y += bfhi(g1.y); }
        if (s2 >= 0) { a0.x += bflo(g2.x); a0.y += bfhi(g2.x); a1.x += bflo(g2.y); a1.y += bfhi(g2.y); }
        if (s3 >= 0) { a0.x += bflo(g3.x); a0.y += bfhi(g3.x); a1.x += bflo(g3.y); a1.y += bfhi(g3.y); }
    }

    a0.x += __shfl_xor(a0.x, 16); a0.y += __shfl_xor(a0.y, 16);
    a1.x += __shfl_xor(a1.x, 16); a1.y += __shfl_xor(a1.y, 16);
    a0.x += __shfl_xor(a0.x, 32); a0.y += __shfl_xor(a0.y, 32);
    a1.x += __shfl_xor(a1.x, 32); a1.y += __shfl_xor(a1.y, 32);

    if (q == 0) {
        float dv = dinv[node];
        float4 bb = *(const float4*)(bias + 4 * fq);
        float v0 = a0.x * dv + bb.x;
        float v1 = a0.y * dv + bb.y;
        float v2 = a1.x * dv + bb.z;
        float v3 = a1.y * dv + bb.w;
        if (RELU) {
            v0 = fmaxf(v0, 0.f); v1 = fmaxf(v1, 0.f);
            v2 = fmaxf(v2, 0.f); v3 = fmaxf(v3, 0.f);
        }
        uint2 pk;
        pk.x = (unsigned int)f2bf(v0) | ((unsigned int)f2bf(v1) << 16);
        pk.y = (unsigned int)f2bf(v2) | ((unsigned int)f2bf(v3) << 16);
        *(((uint2*)Z) + (size_t)node * 16 + fq) = pk;
    }
}

// ---------------- fused pooling + head (batch sorted -> contiguous segments) ----------------

__global__ void pool_head(const unsigned short* __restrict__ Hb, const int* __restrict__ batch,
                          const float* __restrict__ Wl, const float* __restrict__ bl,
                          float* __restrict__ out) {
    int g   = blockIdx.x;
    int tid = threadIdx.x;   // 0..255

    auto lb = [&](int key) {
        int lo = 0, hi = N_NODES;
        while (lo < hi) {
            int mid = (lo + hi) >> 1;
            if (batch[mid] < key) lo = mid + 1; else hi = mid;
        }
        return lo;
    };
    int beg = lb(g);
    int end = lb(g + 1);

    int fq = tid & 15;       // feature quad (features 4fq..4fq+3)
    int rg = tid >> 4;       // 16 row groups
    const uint2* H = (const uint2*)Hb;
    float4 acc = {0.f, 0.f, 0.f, 0.f};
    for (int i = beg + rg; i < end; i += 16) {
        uint2 gg = H[(size_t)i * 16 + fq];
        acc.x += bflo(gg.x); acc.y += bfhi(gg.x);
        acc.z += bflo(gg.y); acc.w += bfhi(gg.y);
    }

    __shared__ float4 s[16][16];
    __shared__ float  pl[64];
    s[rg][fq] = acc;
    __syncthreads();

    if (tid < 16) {
        float4 t = s[0][tid];
        for (int r = 1; r < 16; ++r) {
            t.x += s[r][tid].x; t.y += s[r][tid].y;
            t.z += s[r][tid].z; t.w += s[r][tid].w;
        }
        float inv = 1.0f / fmaxf((float)(end - beg), 1.0f);
        pl[4 * tid]     = t.x * inv;
        pl[4 * tid + 1] = t.y * inv;
        pl[4 * tid + 2] = t.z * inv;
        pl[4 * tid + 3] = t.w * inv;
    }
    __syncthreads();

    if (tid < 64) {
        float p = pl[tid];
        __shared__ float logits[N_CLS];
        for (int c = 0; c < N_CLS; ++c) {
            float v = p * Wl[tid * N_CLS + c];
            for (int off = 32; off; off >>= 1) v += __shfl_xor(v, off);
            if (tid == 0) logits[c] = v + bl[c];
        }
        if (tid == 0) {
            float m = logits[0];
            for (int c = 1; c < N_CLS; ++c) m = fmaxf(m, logits[c]);
            float sum = 0.f;
            for (int c = 0; c < N_CLS; ++c) sum += expf(logits[c] - m);
            float ls = logf(sum);
            for (int c = 0; c < N_CLS; ++c) out[g * N_CLS + c] = logits[c] - m - ls;
        }
    }
}

// ---------------- launch ----------------

extern "C" void kernel_launch(void* const* d_in, const int* in_sizes, int n_in,
                              void* d_out, int out_size, void* d_ws, size_t ws_size,
                              hipStream_t stream) {
    const float* x     = (const float*)d_in[0];
    const int*   ei    = (const int*)d_in[1];
    const int*   batch = (const int*)d_in[2];
    const float* W1    = (const float*)d_in[3];
    const float* b1    = (const float*)d_in[4];
    const float* W2    = (const float*)d_in[5];
    const float* b2    = (const float*)d_in[6];
    const float* Wl    = (const float*)d_in[7];
    const float* bl    = (const float*)d_in[8];
    float*       out   = (float*)d_out;

    char* p = (char*)d_ws;
    auto alloc = [&](size_t bytes) {
        char* r = p;
        p += (bytes + 255) & ~(size_t)255;
        return r;
    };
    int*            bktcnt = (int*)            alloc((size_t)NBKT * 4);
    int*            bktptr = (int*)            alloc((size_t)(NBKT + 1) * 4);
    int*            btail  = (int*)            alloc((size_t)NBKT * 4);
    int*            rowptr = (int*)            alloc((size_t)(N_NODES + 1) * 4);
    float*          dinv   = (float*)          alloc((size_t)N_NODES * 4);
    int*            colsrc = (int*)            alloc((size_t)N_EDGES * 4);
    unsigned int*   bins   = (unsigned int*)   alloc((size_t)N_EDGES * 4);
    unsigned char*  hA8    = (unsigned char*)  alloc((size_t)N_NODES * H_DIM);
    unsigned short* hA     = (unsigned short*) alloc((size_t)N_NODES * H_DIM * 2);
    unsigned short* hB     = (unsigned short*) alloc((size_t)N_NODES * H_DIM * 2);
    unsigned short* Wp1    = (unsigned short*) alloc((size_t)1024 * 8 * 2);
    unsigned short* Wp2    = (unsigned short*) alloc((size_t)512 * 8 * 2);

    hipMemsetAsync(bktcnt, 0, (size_t)NBKT * 4, stream);

    int nb4 = (N_NODES + 3) / 4;
    int gb  = (N_NODES + 63) / 64;

    bkt_count   <<<BIN_NB, 256, 0, stream>>>(ei, bktcnt);
    scan_bkt    <<<1, 512, 0, stream>>>(bktcnt, bktptr, btail);
    bin_edges   <<<BIN_NB, 256, 0, stream>>>(ei, btail, bins);
    bucket_build<<<NBKT, 256, 0, stream>>>(bins, bktptr, rowptr, dinv, colsrc);
    pack_weights<<<6, 256, 0, stream>>>(W1, W2, Wp1, Wp2);

    gemm_mfma<F_IN, false, true><<<gb, 256, 0, stream>>>(x, Wp1, dinv, hA8);   // h1' fp8
    agg_fp8_relu<<<nb4, 256, 0, stream>>>(hA8, dinv, rowptr, colsrc, b1, hB);  // z1 bf16
    gemm_mfma<H_DIM, true, false><<<gb, 256, 0, stream>>>(hB, Wp2, dinv, hA);  // h2' bf16
    agg_fast<0><<<nb4, 256, 0, stream>>>(hA, dinv, rowptr, colsrc, b2, hB);    // z2 bf16
    pool_head<<<N_GRAPH, 256, 0, stream>>>(hB, batch, Wl, bl, out);
}

// Round 11
// 175.955 us; speedup vs baseline: 4.7020x; 1.0088x over previous
//
#include <hip/hip_runtime.h>
#include <hip/hip_fp8.h>

#define N_NODES 100000
#define N_EDGES 1250000
#define F_IN    128
#define H_DIM   64
#define N_CLS   10
#define N_GRAPH 1000

#define NBKT      ((N_NODES + 255) / 256)   // 391 dst-buckets of 256 nodes
#define BIN_T     16
#define BIN_CHUNK (256 * BIN_T)             // 4096 edges per block
#define BIN_NB    ((N_EDGES + BIN_CHUNK - 1) / BIN_CHUNK)

typedef __attribute__((ext_vector_type(8))) short bf16x8;
typedef __attribute__((ext_vector_type(4))) float f32x4;
typedef __attribute__((ext_vector_type(2))) float f32x2;

__device__ __forceinline__ unsigned short f2bf(float f) {  // RNE fp32 -> bf16
    unsigned int u = __builtin_bit_cast(unsigned int, f);
    u += 0x7FFFu + ((u >> 16) & 1u);
    return (unsigned short)(u >> 16);
}
__device__ __forceinline__ float bf2f(unsigned short h) {
    unsigned int u = (unsigned int)h << 16;
    return __builtin_bit_cast(float, u);
}
__device__ __forceinline__ float bflo(unsigned int g) {
    return __builtin_bit_cast(float, g << 16);
}
__device__ __forceinline__ float bfhi(unsigned int g) {
    return __builtin_bit_cast(float, g & 0xFFFF0000u);
}
__device__ __forceinline__ unsigned char ftofp8(float f) {
    __hip_fp8_e4m3 v(f); return v.__x;
}

// ---------------- CSR build (bucketed, no per-node global atomics) ----------------

__global__ void bkt_count(const int* __restrict__ ei, int* __restrict__ bktcnt) {
    __shared__ int hist[NBKT];
    int tid = threadIdx.x;
    for (int b = tid; b < NBKT; b += 256) hist[b] = 0;
    __syncthreads();
    int e0 = blockIdx.x * BIN_CHUNK;
#pragma unroll
    for (int t = 0; t < BIN_T; ++t) {
        int e = e0 + t * 256 + tid;
        if (e < N_EDGES) atomicAdd(&hist[ei[N_EDGES + e] >> 8], 1);
    }
    __syncthreads();
    for (int b = tid; b < NBKT; b += 256)
        if (hist[b]) atomicAdd(&bktcnt[b], hist[b]);
}

__global__ void scan_bkt(const int* __restrict__ bktcnt, int* __restrict__ bktptr,
                         int* __restrict__ btail) {
    __shared__ int s[512];
    int t = threadIdx.x;
    int v = (t < NBKT) ? bktcnt[t] : 0;
    s[t] = v;
    __syncthreads();
    for (int off = 1; off < 512; off <<= 1) {
        int u = (t >= off) ? s[t - off] : 0;
        __syncthreads();
        s[t] += u;
        __syncthreads();
    }
    if (t < NBKT) { int ex = s[t] - v; bktptr[t] = ex; btail[t] = ex; }
    if (t == 0) bktptr[NBKT] = N_EDGES;
}

__global__ void bin_edges(const int* __restrict__ ei, int* __restrict__ btail,
                          unsigned int* __restrict__ bins) {
    __shared__ int hist[NBKT];
    __shared__ int base[NBKT];
    int tid = threadIdx.x;
    for (int b = tid; b < NBKT; b += 256) hist[b] = 0;
    __syncthreads();
    int e0 = blockIdx.x * BIN_CHUNK;
    unsigned short rank[BIN_T];
#pragma unroll
    for (int t = 0; t < BIN_T; ++t) {
        int e = e0 + t * 256 + tid;
        int r = 0;
        if (e < N_EDGES) {
            int b = ei[N_EDGES + e] >> 8;
            r = atomicAdd(&hist[b], 1);
        }
        rank[t] = (unsigned short)r;
    }
    __syncthreads();
    for (int b = tid; b < NBKT; b += 256) {
        int c = hist[b];
        base[b] = c ? atomicAdd(&btail[b], c) : 0;
    }
    __syncthreads();
#pragma unroll
    for (int t = 0; t < BIN_T; ++t) {
        int e = e0 + t * 256 + tid;
        if (e < N_EDGES) {
            int src = ei[e];
            int dst = ei[N_EDGES + e];
            int b = dst >> 8;
            bins[base[b] + (int)rank[t]] = (unsigned int)src | ((unsigned int)(dst & 255) << 17);
        }
    }
}

__global__ void bucket_build(const unsigned int* __restrict__ bins, const int* __restrict__ bktptr,
                             int* __restrict__ rowptr, float* __restrict__ dinv,
                             int* __restrict__ colsrc) {
    __shared__ int cnt[256];
    __shared__ int pfx[256];
    __shared__ int cur[256];
    __shared__ int ws[4];
    int bkt  = blockIdx.x;
    int base = bkt << 8;
    int tid  = threadIdx.x;
    int nn   = N_NODES - base; if (nn > 256) nn = 256;
    int pbeg = bktptr[bkt], pend = bktptr[bkt + 1];

    cnt[tid] = 0; cur[tid] = 0;
    __syncthreads();
    for (int p = pbeg + tid; p < pend; p += 256)
        atomicAdd(&cnt[bins[p] >> 17], 1);
    __syncthreads();

    int lane = tid & 63, wid = tid >> 6;
    int v   = cnt[tid];
    int inc = v;
    for (int off = 1; off < 64; off <<= 1) {
        int u = __shfl_up(inc, off);
        if (lane >= off) inc += u;
    }
    if (lane == 63) ws[wid] = inc;
    __syncthreads();
    int woff = 0;
    for (int w = 0; w < wid; ++w) woff += ws[w];
    pfx[tid] = woff + inc - v;   // exclusive prefix within bucket
    __syncthreads();

    if (tid < nn) {
        rowptr[base + tid] = pbeg + pfx[tid];
        dinv[base + tid]   = rsqrtf((float)v + 1.0f);   // +1 self-loop
    }
    if (bkt == NBKT - 1 && tid == 0) rowptr[N_NODES] = N_EDGES;

    for (int p = pbeg + tid; p < pend; p += 256) {
        unsigned int pk = bins[p];
        int ld  = (int)(pk >> 17);
        int loc = atomicAdd(&cur[ld], 1);
        colsrc[pbeg + pfx[ld] + loc] = (int)(pk & 0x1FFFFu);
    }
}

// ---------------- weight packing (fp32 -> bf16 MFMA B-fragment order) ----------------

__global__ void pack_weights(const float* __restrict__ W1, const float* __restrict__ W2,
                             unsigned short* __restrict__ Wp1, unsigned short* __restrict__ Wp2) {
    int idx = blockIdx.x * 256 + threadIdx.x;   // 0..1535
    if (idx < 1024) {                           // W1: K=128 -> 4 chunks x 4 tiles
        int l = idx & 63, tc = idx >> 6;
        int c = tc & 3, t = tc >> 2;
        for (int j = 0; j < 8; ++j)
            Wp1[idx * 8 + j] = f2bf(W1[(c * 32 + (l >> 4) * 8 + j) * H_DIM + t * 16 + (l & 15)]);
    } else if (idx < 1536) {                    // W2: K=64 -> 2 chunks x 4 tiles
        int i2 = idx - 1024;
        int l = i2 & 63, tc = i2 >> 6;
        int c = tc & 1, t = tc >> 1;
        for (int j = 0; j < 8; ++j)
            Wp2[i2 * 8 + j] = f2bf(W2[(c * 32 + (l >> 4) * 8 + j) * H_DIM + t * 16 + (l & 15)]);
    }
}

// ---------------- MFMA GEMM:  Y[row][col] = (A[row][:] @ W[:,col]) * dinv[row] -> fp8 ------

template<int K, bool ABF>
__global__ void gemm_mfma(const void* __restrict__ Ap, const unsigned short* __restrict__ Wp,
                          const float* __restrict__ dinv, unsigned char* __restrict__ Y) {
    int lane = threadIdx.x & 63;
    int wave = threadIdx.x >> 6;
    int l16 = lane & 15, lhi = lane >> 4;
    int row0 = blockIdx.x * 64 + wave * 16;
    int arow = row0 + l16;
    bool aok = (arow < N_NODES);

    f32x4 acc[4];
#pragma unroll
    for (int t = 0; t < 4; ++t) acc[t] = (f32x4){0.f, 0.f, 0.f, 0.f};

#pragma unroll
    for (int c = 0; c < K / 32; ++c) {
        bf16x8 a;
        if (ABF) {
            if (aok) a = *(const bf16x8*)((const unsigned short*)Ap + (size_t)arow * K + c * 32 + lhi * 8);
            else     a = (bf16x8){0, 0, 0, 0, 0, 0, 0, 0};
        } else {
            if (aok) {
                const float* Af = (const float*)Ap + (size_t)arow * K + c * 32 + lhi * 8;
                float4 f0 = *(const float4*)(Af);
                float4 f1 = *(const float4*)(Af + 4);
                a = (bf16x8){(short)f2bf(f0.x), (short)f2bf(f0.y), (short)f2bf(f0.z), (short)f2bf(f0.w),
                             (short)f2bf(f1.x), (short)f2bf(f1.y), (short)f2bf(f1.z), (short)f2bf(f1.w)};
            } else a = (bf16x8){0, 0, 0, 0, 0, 0, 0, 0};
        }
#pragma unroll
        for (int t = 0; t < 4; ++t) {
            bf16x8 b = *(const bf16x8*)(Wp + ((size_t)(t * (K / 32) + c) * 64 + lane) * 8);
            acc[t] = __builtin_amdgcn_mfma_f32_16x16x32_bf16(a, b, acc[t], 0, 0, 0);
        }
    }

#pragma unroll
    for (int r = 0; r < 4; ++r) {
        int row = row0 + lhi * 4 + r;
        if (row < N_NODES) {
            float dv = dinv[row];
#pragma unroll
            for (int t = 0; t < 4; ++t)
                Y[(size_t)row * H_DIM + t * 16 + l16] = ftofp8(acc[t][r] * dv);
        }
    }
}

// ---------------- aggregation: fp8 gather source (64B/row, 8 edge slots/wave) --------------
// out = [relu](dinv[i]*(sum_{e:dst=i} h'[src] + h'[i]) + b), h' fp8 pre-scaled; out bf16.
// Unpack via hardware v_cvt_pk_f32_fp8 (2 fp8 -> 2 f32 per VALU op).

template<int RELU>
__global__ void agg_fp8(const unsigned char* __restrict__ Hq, const float* __restrict__ dinv,
                        const int* __restrict__ rowptr, const int* __restrict__ colsrc,
                        const float* __restrict__ bias, unsigned short* __restrict__ Z) {
    int tid  = threadIdx.x;
    int node = blockIdx.x * 4 + (tid >> 6);
    int lane = tid & 63;
    if (node >= N_NODES) return;
    int q  = lane >> 3;          // edge slot 0..7
    int f8 = lane & 7;           // feature-octet: features 8f8..8f8+7

    const uint2* H = (const uint2*)Hq;   // 8B granules; 8 per row

    float a[8];
#pragma unroll
    for (int i = 0; i < 8; ++i) a[i] = 0.f;

    auto acc8 = [&](uint2 g) {
        f32x2 p0 = __builtin_amdgcn_cvt_pk_f32_fp8((int)g.x, false);
        f32x2 p1 = __builtin_amdgcn_cvt_pk_f32_fp8((int)g.x, true);
        f32x2 p2 = __builtin_amdgcn_cvt_pk_f32_fp8((int)g.y, false);
        f32x2 p3 = __builtin_amdgcn_cvt_pk_f32_fp8((int)g.y, true);
        a[0] += p0.x; a[1] += p0.y; a[2] += p1.x; a[3] += p1.y;
        a[4] += p2.x; a[5] += p2.y; a[6] += p3.x; a[7] += p3.y;
    };

    if (q == 0) acc8(H[(size_t)node * 8 + f8]);   // self term once

    int beg = rowptr[node], end = rowptr[node + 1];
    int p = beg;
    for (; p + 16 <= end; p += 16) {
        int s0 = colsrc[p + q];
        int s1 = colsrc[p + 8 + q];
        uint2 g0 = H[(size_t)s0 * 8 + f8];
        uint2 g1 = H[(size_t)s1 * 8 + f8];
        acc8(g0); acc8(g1);
    }
    {   // masked tail: < 16 edges remain
        int e  = p + q;
        int s0 = (e     < end) ? colsrc[e]     : -1;
        int s1 = (e + 8 < end) ? colsrc[e + 8] : -1;
        uint2 g0 = H[(size_t)(s0 < 0 ? 0 : s0) * 8 + f8];
        uint2 g1 = H[(size_t)(s1 < 0 ? 0 : s1) * 8 + f8];
        if (s0 >= 0) acc8(g0);
        if (s1 >= 0) acc8(g1);
    }

    // reduce across the 8 edge slots (same features, different edges)
#pragma unroll
    for (int off = 8; off < 64; off <<= 1) {
#pragma unroll
        for (int i = 0; i < 8; ++i) a[i] += __shfl_xor(a[i], off);
    }

    if (q == 0) {
        float dv = dinv[node];
        float4 b0 = *(const float4*)(bias + 8 * f8);
        float4 b1 = *(const float4*)(bias + 8 * f8 + 4);
        float v[8];
        v[0] = a[0] * dv + b0.x; v[1] = a[1] * dv + b0.y;
        v[2] = a[2] * dv + b0.z; v[3] = a[3] * dv + b0.w;
        v[4] = a[4] * dv + b1.x; v[5] = a[5] * dv + b1.y;
        v[6] = a[6] * dv + b1.z; v[7] = a[7] * dv + b1.w;
        if (RELU) {
#pragma unroll
            for (int i = 0; i < 8; ++i) v[i] = fmaxf(v[i], 0.f);
        }
        uint4 pk;
        pk.x = (unsigned int)f2bf(v[0]) | ((unsigned int)f2bf(v[1]) << 16);
        pk.y = (unsigned int)f2bf(v[2]) | ((unsigned int)f2bf(v[3]) << 16);
        pk.z = (unsigned int)f2bf(v[4]) | ((unsigned int)f2bf(v[5]) << 16);
        pk.w = (unsigned int)f2bf(v[6]) | ((unsigned int)f2bf(v[7]) << 16);
        *(((uint4*)Z) + (size_t)node * 8 + f8) = pk;
    }
}

// ---------------- fused pooling + head (batch sorted -> contiguous segments) ----------------

__global__ void pool_head(const unsigned short* __restrict__ Hb, const int* __restrict__ batch,
                          const float* __restrict__ Wl, const float* __restrict__ bl,
                          float* __restrict__ out) {
    int g   = blockIdx.x;
    int tid = threadIdx.x;   // 0..255

    auto lb = [&](int key) {
        int lo = 0, hi = N_NODES;
        while (lo < hi) {
            int mid = (lo + hi) >> 1;
            if (batch[mid] < key) lo = mid + 1; else hi = mid;
        }
        return lo;
    };
    int beg = lb(g);
    int end = lb(g + 1);

    int fq = tid & 15;       // feature quad (features 4fq..4fq+3)
    int rg = tid >> 4;       // 16 row groups
    const uint2* H = (const uint2*)Hb;
    float4 acc = {0.f, 0.f, 0.f, 0.f};
    for (int i = beg + rg; i < end; i += 16) {
        uint2 gg = H[(size_t)i * 16 + fq];
        acc.x += bflo(gg.x); acc.y += bfhi(gg.x);
        acc.z += bflo(gg.y); acc.w += bfhi(gg.y);
    }

    __shared__ float4 s[16][16];
    __shared__ float  pl[64];
    s[rg][fq] = acc;
    __syncthreads();

    if (tid < 16) {
        float4 t = s[0][tid];
        for (int r = 1; r < 16; ++r) {
            t.x += s[r][tid].x; t.y += s[r][tid].y;
            t.z += s[r][tid].z; t.w += s[r][tid].w;
        }
        float inv = 1.0f / fmaxf((float)(end - beg), 1.0f);
        pl[4 * tid]     = t.x * inv;
        pl[4 * tid + 1] = t.y * inv;
        pl[4 * tid + 2] = t.z * inv;
        pl[4 * tid + 3] = t.w * inv;
    }
    __syncthreads();

    if (tid < 64) {
        float p = pl[tid];
        __shared__ float logits[N_CLS];
        for (int c = 0; c < N_CLS; ++c) {
            float v = p * Wl[tid * N_CLS + c];
            for (int off = 32; off; off >>= 1) v += __shfl_xor(v, off);
            if (tid == 0) logits[c] = v + bl[c];
        }
        if (tid == 0) {
            float m = logits[0];
            for (int c = 1; c < N_CLS; ++c) m = fmaxf(m, logits[c]);
            float sum = 0.f;
            for (int c = 0; c < N_CLS; ++c) sum += expf(logits[c] - m);
            float ls = logf(sum);
            for (int c = 0; c < N_CLS; ++c) out[g * N_CLS + c] = logits[c] - m - ls;
        }
    }
}

// ---------------- launch ----------------

extern "C" void kernel_launch(void* const* d_in, const int* in_sizes, int n_in,
                              void* d_out, int out_size, void* d_ws, size_t ws_size,
                              hipStream_t stream) {
    const float* x     = (const float*)d_in[0];
    const int*   ei    = (const int*)d_in[1];
    const int*   batch = (const int*)d_in[2];
    const float* W1    = (const float*)d_in[3];
    const float* b1    = (const float*)d_in[4];
    const float* W2    = (const float*)d_in[5];
    const float* b2    = (const float*)d_in[6];
    const float* Wl    = (const float*)d_in[7];
    const float* bl    = (const float*)d_in[8];
    float*       out   = (float*)d_out;

    char* p = (char*)d_ws;
    auto alloc = [&](size_t bytes) {
        char* r = p;
        p += (bytes + 255) & ~(size_t)255;
        return r;
    };
    int*            bktcnt = (int*)            alloc((size_t)NBKT * 4);
    int*            bktptr = (int*)            alloc((size_t)(NBKT + 1) * 4);
    int*            btail  = (int*)            alloc((size_t)NBKT * 4);
    int*            rowptr = (int*)            alloc((size_t)(N_NODES + 1) * 4);
    float*          dinv   = (float*)          alloc((size_t)N_NODES * 4);
    int*            colsrc = (int*)            alloc((size_t)N_EDGES * 4);
    unsigned int*   bins   = (unsigned int*)   alloc((size_t)N_EDGES * 4);
    unsigned char*  hA8    = (unsigned char*)  alloc((size_t)N_NODES * H_DIM);
    unsigned short* hB     = (unsigned short*) alloc((size_t)N_NODES * H_DIM * 2);
    unsigned short* Wp1    = (unsigned short*) alloc((size_t)1024 * 8 * 2);
    unsigned short* Wp2    = (unsigned short*) alloc((size_t)512 * 8 * 2);

    hipMemsetAsync(bktcnt, 0, (size_t)NBKT * 4, stream);

    int nb4 = (N_NODES + 3) / 4;
    int gb  = (N_NODES + 63) / 64;

    bkt_count   <<<BIN_NB, 256, 0, stream>>>(ei, bktcnt);
    scan_bkt    <<<1, 512, 0, stream>>>(bktcnt, bktptr, btail);
    bin_edges   <<<BIN_NB, 256, 0, stream>>>(ei, btail, bins);
    bucket_build<<<NBKT, 256, 0, stream>>>(bins, bktptr, rowptr, dinv, colsrc);
    pack_weights<<<6, 256, 0, stream>>>(W1, W2, Wp1, Wp2);

    gemm_mfma<F_IN, false><<<gb, 256, 0, stream>>>(x, Wp1, dinv, hA8);        // h1' fp8
    agg_fp8<1><<<nb4, 256, 0, stream>>>(hA8, dinv, rowptr, colsrc, b1, hB);   // z1 bf16
    gemm_mfma<H_DIM, true><<<gb, 256, 0, stream>>>(hB, Wp2, dinv, hA8);       // h2' fp8
    agg_fp8<0><<<nb4, 256, 0, stream>>>(hA8, dinv, rowptr, colsrc, b2, hB);   // z2 bf16
    pool_head<<<N_GRAPH, 256, 0, stream>>>(hB, batch, Wl, bl, out);
}

// Round 12
// 153.848 us; speedup vs baseline: 5.3776x; 1.1437x over previous
//
#include <hip/hip_runtime.h>
#include <hip/hip_fp8.h>

#define N_NODES 100000
#define N_EDGES 1250000
#define F_IN    128
#define H_DIM   64
#define N_CLS   10
#define N_GRAPH 1000

#define NBKT      ((N_NODES + 255) / 256)   // 391 dst-buckets of 256 nodes
#define BKT_CAP   3584                      // >= max bucket load (3197 + 6.8 sigma)
#define BINS_CAP  (NBKT * BKT_CAP)
#define BIN_T     16
#define BIN_CHUNK (256 * BIN_T)             // 4096 edges per block
#define BIN_NB    ((N_EDGES + BIN_CHUNK - 1) / BIN_CHUNK)

typedef __attribute__((ext_vector_type(8))) short bf16x8;
typedef __attribute__((ext_vector_type(4))) float f32x4;
typedef __attribute__((ext_vector_type(2))) float f32x2;

__device__ __forceinline__ unsigned short f2bf(float f) {  // RNE fp32 -> bf16
    unsigned int u = __builtin_bit_cast(unsigned int, f);
    u += 0x7FFFu + ((u >> 16) & 1u);
    return (unsigned short)(u >> 16);
}
__device__ __forceinline__ float bf2f(unsigned short h) {
    unsigned int u = (unsigned int)h << 16;
    return __builtin_bit_cast(float, u);
}
__device__ __forceinline__ float bflo(unsigned int g) {
    return __builtin_bit_cast(float, g << 16);
}
__device__ __forceinline__ float bfhi(unsigned int g) {
    return __builtin_bit_cast(float, g & 0xFFFF0000u);
}
__device__ __forceinline__ unsigned char ftofp8(float f) {
    __hip_fp8_e4m3 v(f); return v.__x;
}

// ---------------- CSR build (fixed-capacity buckets; no count/scan passes) ----------------

__global__ void init_btail(int* __restrict__ btail) {
    int b = blockIdx.x * 256 + threadIdx.x;
    if (b < NBKT) btail[b] = b * BKT_CAP;
}

// Bin edges by dst bucket (dst>>8). Entry: src (17b) | local-dst (8b) << 17.
// Bucket b's region in `bins` starts at b*BKT_CAP; btail[b] is the append cursor.
__global__ void bin_edges(const int* __restrict__ ei, int* __restrict__ btail,
                          unsigned int* __restrict__ bins) {
    __shared__ int hist[NBKT];
    __shared__ int base[NBKT];
    int tid = threadIdx.x;
    for (int b = tid; b < NBKT; b += 256) hist[b] = 0;
    __syncthreads();
    int e0 = blockIdx.x * BIN_CHUNK;
    unsigned short rank[BIN_T];
#pragma unroll
    for (int t = 0; t < BIN_T; ++t) {
        int e = e0 + t * 256 + tid;
        int r = 0;
        if (e < N_EDGES) {
            int b = ei[N_EDGES + e] >> 8;
            r = atomicAdd(&hist[b], 1);
        }
        rank[t] = (unsigned short)r;
    }
    __syncthreads();
    for (int b = tid; b < NBKT; b += 256) {
        int c = hist[b];
        base[b] = c ? atomicAdd(&btail[b], c) : 0;
    }
    __syncthreads();
#pragma unroll
    for (int t = 0; t < BIN_T; ++t) {
        int e = e0 + t * 256 + tid;
        if (e < N_EDGES) {
            int src = ei[e];
            int dst = ei[N_EDGES + e];
            int b = dst >> 8;
            int idx = base[b] + (int)rank[t];
            if (idx >= BINS_CAP) idx = BINS_CAP - 1;   // impossible-overflow guard
            bins[idx] = (unsigned int)src | ((unsigned int)(dst & 255) << 17);
        }
    }
}

// One block per bucket: per-node counts (LDS), block scan -> packed rowdeg
// (beg | deg<<22) + dinv, then dense in-bucket scatter into colsrc.
__global__ void bucket_build(const unsigned int* __restrict__ bins, const int* __restrict__ btail,
                             int* __restrict__ rowdeg, float* __restrict__ dinv,
                             int* __restrict__ colsrc) {
    __shared__ int cnt[256];
    __shared__ int pfx[256];
    __shared__ int cur[256];
    __shared__ int ws[4];
    int bkt  = blockIdx.x;
    int base = bkt << 8;
    int tid  = threadIdx.x;
    int nn   = N_NODES - base; if (nn > 256) nn = 256;
    int pbeg = bkt * BKT_CAP, pend = btail[bkt];

    cnt[tid] = 0; cur[tid] = 0;
    __syncthreads();
    for (int p = pbeg + tid; p < pend; p += 256)
        atomicAdd(&cnt[bins[p] >> 17], 1);
    __syncthreads();

    int lane = tid & 63, wid = tid >> 6;
    int v   = cnt[tid];
    int inc = v;
    for (int off = 1; off < 64; off <<= 1) {
        int u = __shfl_up(inc, off);
        if (lane >= off) inc += u;
    }
    if (lane == 63) ws[wid] = inc;
    __syncthreads();
    int woff = 0;
    for (int w = 0; w < wid; ++w) woff += ws[w];
    pfx[tid] = woff + inc - v;   // exclusive prefix within bucket
    __syncthreads();

    if (tid < nn) {
        rowdeg[base + tid] = (pbeg + pfx[tid]) | (v << 22);
        dinv[base + tid]   = rsqrtf((float)v + 1.0f);   // +1 self-loop
    }

    for (int p = pbeg + tid; p < pend; p += 256) {
        unsigned int pk = bins[p];
        int ld  = (int)(pk >> 17);
        int loc = atomicAdd(&cur[ld], 1);
        colsrc[pbeg + pfx[ld] + loc] = (int)(pk & 0x1FFFFu);
    }
}

// ---------------- weight packing (fp32 -> bf16 MFMA B-fragment order) ----------------

__global__ void pack_weights(const float* __restrict__ W1, const float* __restrict__ W2,
                             unsigned short* __restrict__ Wp1, unsigned short* __restrict__ Wp2) {
    int idx = blockIdx.x * 256 + threadIdx.x;   // 0..1535
    if (idx < 1024) {                           // W1: K=128 -> 4 chunks x 4 tiles
        int l = idx & 63, tc = idx >> 6;
        int c = tc & 3, t = tc >> 2;
        for (int j = 0; j < 8; ++j)
            Wp1[idx * 8 + j] = f2bf(W1[(c * 32 + (l >> 4) * 8 + j) * H_DIM + t * 16 + (l & 15)]);
    } else if (idx < 1536) {                    // W2: K=64 -> 2 chunks x 4 tiles
        int i2 = idx - 1024;
        int l = i2 & 63, tc = i2 >> 6;
        int c = tc & 1, t = tc >> 1;
        for (int j = 0; j < 8; ++j)
            Wp2[i2 * 8 + j] = f2bf(W2[(c * 32 + (l >> 4) * 8 + j) * H_DIM + t * 16 + (l & 15)]);
    }
}

// ---------------- MFMA GEMM:  Y[row][col] = (A[row][:] @ W[:,col]) * dinv[row] -> fp8 ------

template<int K, bool ABF>
__global__ void gemm_mfma(const void* __restrict__ Ap, const unsigned short* __restrict__ Wp,
                          const float* __restrict__ dinv, unsigned char* __restrict__ Y) {
    int lane = threadIdx.x & 63;
    int wave = threadIdx.x >> 6;
    int l16 = lane & 15, lhi = lane >> 4;
    int row0 = blockIdx.x * 64 + wave * 16;
    int arow = row0 + l16;
    bool aok = (arow < N_NODES);

    f32x4 acc[4];
#pragma unroll
    for (int t = 0; t < 4; ++t) acc[t] = (f32x4){0.f, 0.f, 0.f, 0.f};

#pragma unroll
    for (int c = 0; c < K / 32; ++c) {
        bf16x8 a;
        if (ABF) {
            if (aok) a = *(const bf16x8*)((const unsigned short*)Ap + (size_t)arow * K + c * 32 + lhi * 8);
            else     a = (bf16x8){0, 0, 0, 0, 0, 0, 0, 0};
        } else {
            if (aok) {
                const float* Af = (const float*)Ap + (size_t)arow * K + c * 32 + lhi * 8;
                float4 f0 = *(const float4*)(Af);
                float4 f1 = *(const float4*)(Af + 4);
                a = (bf16x8){(short)f2bf(f0.x), (short)f2bf(f0.y), (short)f2bf(f0.z), (short)f2bf(f0.w),
                             (short)f2bf(f1.x), (short)f2bf(f1.y), (short)f2bf(f1.z), (short)f2bf(f1.w)};
            } else a = (bf16x8){0, 0, 0, 0, 0, 0, 0, 0};
        }
#pragma unroll
        for (int t = 0; t < 4; ++t) {
            bf16x8 b = *(const bf16x8*)(Wp + ((size_t)(t * (K / 32) + c) * 64 + lane) * 8);
            acc[t] = __builtin_amdgcn_mfma_f32_16x16x32_bf16(a, b, acc[t], 0, 0, 0);
        }
    }

#pragma unroll
    for (int r = 0; r < 4; ++r) {
        int row = row0 + lhi * 4 + r;
        if (row < N_NODES) {
            float dv = dinv[row];
#pragma unroll
            for (int t = 0; t < 4; ++t)
                Y[(size_t)row * H_DIM + t * 16 + l16] = ftofp8(acc[t][r] * dv);
        }
    }
}

// ---------------- aggregation: fp8 gather, packed f32x2 accum, LDS transpose-reduce --------
// out = [relu](dinv[i]*(sum_{e:dst=i} h'[src] + h'[i]) + b), h' fp8 pre-scaled; out bf16.

template<int RELU>
__global__ void agg_fp8(const unsigned char* __restrict__ Hq, const float* __restrict__ dinv,
                        const int* __restrict__ rowdeg, const int* __restrict__ colsrc,
                        const float* __restrict__ bias, unsigned short* __restrict__ Z) {
    __shared__ float scr[4][8 * 66];    // per-wave 8 slots x (64 feats + 2 pad), 2-way banks
    int tid  = threadIdx.x;
    int wave = tid >> 6;
    int lane = tid & 63;
    int node = blockIdx.x * 4 + wave;   // grid is exact: 25000 blocks x 4 nodes
    int q  = lane >> 3;                 // edge slot 0..7
    int f8 = lane & 7;                  // feature-octet

    const uint2* H = (const uint2*)Hq;

    f32x2 a01 = {0.f, 0.f}, a23 = {0.f, 0.f}, a45 = {0.f, 0.f}, a67 = {0.f, 0.f};
    auto acc8 = [&](uint2 g) {
        a01 += __builtin_amdgcn_cvt_pk_f32_fp8((int)g.x, false);
        a23 += __builtin_amdgcn_cvt_pk_f32_fp8((int)g.x, true);
        a45 += __builtin_amdgcn_cvt_pk_f32_fp8((int)g.y, false);
        a67 += __builtin_amdgcn_cvt_pk_f32_fp8((int)g.y, true);
    };

    if (q == 0) acc8(H[(size_t)node * 8 + f8]);   // self term once

    int rd  = rowdeg[node];
    int beg = rd & 0x3FFFFF;
    int end = beg + (int)((unsigned)rd >> 22);
    int p = beg;
    for (; p + 16 <= end; p += 16) {
        int s0 = colsrc[p + q];
        int s1 = colsrc[p + 8 + q];
        uint2 g0 = H[(size_t)s0 * 8 + f8];
        uint2 g1 = H[(size_t)s1 * 8 + f8];
        acc8(g0); acc8(g1);
    }
    {   // masked tail: < 16 edges remain
        int e  = p + q;
        int s0 = (e     < end) ? colsrc[e]     : -1;
        int s1 = (e + 8 < end) ? colsrc[e + 8] : -1;
        uint2 g0 = H[(size_t)(s0 < 0 ? 0 : s0) * 8 + f8];
        uint2 g1 = H[(size_t)(s1 < 0 ? 0 : s1) * 8 + f8];
        if (s0 >= 0) acc8(g0);
        if (s1 >= 0) acc8(g1);
    }

    // transpose via LDS: scr[wave][q*66 + f] = partial of feature f from slot q
    {
        float* row = &scr[wave][q * 66 + f8 * 8];
        *(f32x2*)(row + 0) = a01;
        *(f32x2*)(row + 2) = a23;
        *(f32x2*)(row + 4) = a45;
        *(f32x2*)(row + 6) = a67;
    }
    __syncthreads();

    // lane f sums its feature column over the 8 slots
    const float* col = &scr[wave][lane];
    float s = col[0];
#pragma unroll
    for (int qq = 1; qq < 8; ++qq) s += col[qq * 66];

    float v = s * dinv[node] + bias[lane];
    if (RELU) v = fmaxf(v, 0.f);
    Z[(size_t)node * H_DIM + lane] = f2bf(v);
}

// ---------------- fused pooling + head (batch sorted -> contiguous segments) ----------------

__global__ void pool_head(const unsigned short* __restrict__ Hb, const int* __restrict__ batch,
                          const float* __restrict__ Wl, const float* __restrict__ bl,
                          float* __restrict__ out) {
    int g   = blockIdx.x;
    int tid = threadIdx.x;   // 0..255

    auto lb = [&](int key) {
        int lo = 0, hi = N_NODES;
        while (lo < hi) {
            int mid = (lo + hi) >> 1;
            if (batch[mid] < key) lo = mid + 1; else hi = mid;
        }
        return lo;
    };
    int beg = lb(g);
    int end = lb(g + 1);

    int fq = tid & 15;       // feature quad (features 4fq..4fq+3)
    int rg = tid >> 4;       // 16 row groups
    const uint2* H = (const uint2*)Hb;
    float4 acc = {0.f, 0.f, 0.f, 0.f};
    for (int i = beg + rg; i < end; i += 16) {
        uint2 gg = H[(size_t)i * 16 + fq];
        acc.x += bflo(gg.x); acc.y += bfhi(gg.x);
        acc.z += bflo(gg.y); acc.w += bfhi(gg.y);
    }

    __shared__ float4 s[16][16];
    __shared__ float  pl[64];
    s[rg][fq] = acc;
    __syncthreads();

    if (tid < 16) {
        float4 t = s[0][tid];
        for (int r = 1; r < 16; ++r) {
            t.x += s[r][tid].x; t.y += s[r][tid].y;
            t.z += s[r][tid].z; t.w += s[r][tid].w;
        }
        float inv = 1.0f / fmaxf((float)(end - beg), 1.0f);
        pl[4 * tid]     = t.x * inv;
        pl[4 * tid + 1] = t.y * inv;
        pl[4 * tid + 2] = t.z * inv;
        pl[4 * tid + 3] = t.w * inv;
    }
    __syncthreads();

    if (tid < 64) {
        float p = pl[tid];
        __shared__ float logits[N_CLS];
        for (int c = 0; c < N_CLS; ++c) {
            float v = p * Wl[tid * N_CLS + c];
            for (int off = 32; off; off >>= 1) v += __shfl_xor(v, off);
            if (tid == 0) logits[c] = v + bl[c];
        }
        if (tid == 0) {
            float m = logits[0];
            for (int c = 1; c < N_CLS; ++c) m = fmaxf(m, logits[c]);
            float sum = 0.f;
            for (int c = 0; c < N_CLS; ++c) sum += expf(logits[c] - m);
            float ls = logf(sum);
            for (int c = 0; c < N_CLS; ++c) out[g * N_CLS + c] = logits[c] - m - ls;
        }
    }
}

// ---------------- launch ----------------

extern "C" void kernel_launch(void* const* d_in, const int* in_sizes, int n_in,
                              void* d_out, int out_size, void* d_ws, size_t ws_size,
                              hipStream_t stream) {
    const float* x     = (const float*)d_in[0];
    const int*   ei    = (const int*)d_in[1];
    const int*   batch = (const int*)d_in[2];
    const float* W1    = (const float*)d_in[3];
    const float* b1    = (const float*)d_in[4];
    const float* W2    = (const float*)d_in[5];
    const float* b2    = (const float*)d_in[6];
    const float* Wl    = (const float*)d_in[7];
    const float* bl    = (const float*)d_in[8];
    float*       out   = (float*)d_out;

    char* p = (char*)d_ws;
    auto alloc = [&](size_t bytes) {
        char* r = p;
        p += (bytes + 255) & ~(size_t)255;
        return r;
    };
    int*            btail  = (int*)            alloc((size_t)NBKT * 4);
    int*            rowdeg = (int*)            alloc((size_t)N_NODES * 4);
    float*          dinv   = (float*)          alloc((size_t)N_NODES * 4);
    int*            colsrc = (int*)            alloc((size_t)BINS_CAP * 4);
    unsigned int*   bins   = (unsigned int*)   alloc((size_t)BINS_CAP * 4);
    unsigned char*  hA8    = (unsigned char*)  alloc((size_t)N_NODES * H_DIM);
    unsigned short* hB     = (unsigned short*) alloc((size_t)N_NODES * H_DIM * 2);
    unsigned short* Wp1    = (unsigned short*) alloc((size_t)1024 * 8 * 2);
    unsigned short* Wp2    = (unsigned short*) alloc((size_t)512 * 8 * 2);

    int nb4 = (N_NODES + 3) / 4;   // 25000 (exact)
    int gb  = (N_NODES + 63) / 64;

    init_btail  <<<2, 256, 0, stream>>>(btail);
    bin_edges   <<<BIN_NB, 256, 0, stream>>>(ei, btail, bins);
    bucket_build<<<NBKT, 256, 0, stream>>>(bins, btail, rowdeg, dinv, colsrc);
    pack_weights<<<6, 256, 0, stream>>>(W1, W2, Wp1, Wp2);

    gemm_mfma<F_IN, false><<<gb, 256, 0, stream>>>(x, Wp1, dinv, hA8);        // h1' fp8
    agg_fp8<1><<<nb4, 256, 0, stream>>>(hA8, dinv, rowdeg, colsrc, b1, hB);   // z1 bf16
    gemm_mfma<H_DIM, true><<<gb, 256, 0, stream>>>(hB, Wp2, dinv, hA8);       // h2' fp8
    agg_fp8<0><<<nb4, 256, 0, stream>>>(hA8, dinv, rowdeg, colsrc, b2, hB);   // z2 bf16
    pool_head<<<N_GRAPH, 256, 0, stream>>>(hB, batch, Wl, bl, out);
}

// Round 13
// 148.563 us; speedup vs baseline: 5.5689x; 1.0356x over previous
//
#include <hip/hip_runtime.h>
#include <hip/hip_fp8.h>

#define N_NODES 100000
#define N_EDGES 1250000
#define F_IN    128
#define H_DIM   64
#define N_CLS   10
#define N_GRAPH 1000

#define NBKT      ((N_NODES + 255) / 256)   // 391 dst-buckets of 256 nodes
#define BKT_CAP   3584                      // >= max bucket load (3200 + 6.8 sigma)
#define BINS_CAP  (NBKT * BKT_CAP)
#define BIN_T     16
#define BIN_CHUNK (256 * BIN_T)             // 4096 edges per block
#define BIN_NB    ((N_EDGES + BIN_CHUNK - 1) / BIN_CHUNK)

typedef __attribute__((ext_vector_type(8))) short bf16x8;
typedef __attribute__((ext_vector_type(4))) float f32x4;
typedef __attribute__((ext_vector_type(2))) float f32x2;

__device__ __forceinline__ unsigned short f2bf(float f) {  // RNE fp32 -> bf16
    unsigned int u = __builtin_bit_cast(unsigned int, f);
    u += 0x7FFFu + ((u >> 16) & 1u);
    return (unsigned short)(u >> 16);
}
__device__ __forceinline__ float bf2f(unsigned short h) {
    unsigned int u = (unsigned int)h << 16;
    return __builtin_bit_cast(float, u);
}
__device__ __forceinline__ float bflo(unsigned int g) {
    return __builtin_bit_cast(float, g << 16);
}
__device__ __forceinline__ float bfhi(unsigned int g) {
    return __builtin_bit_cast(float, g & 0xFFFF0000u);
}
__device__ __forceinline__ unsigned char ftofp8(float f) {
    __hip_fp8_e4m3 v(f); return v.__x;
}

// ---------------- setup: btail init + weight packing (one kernel) ----------------
// Wp layout: B-frag for (col-tile t, k-chunk c): lane l, elem j holds
// W[c*32 + (l>>4)*8 + j][t*16 + (l&15)], packed at Wp[((t*(K/32)+c)*64+l)*8+j].

__global__ void setup(const float* __restrict__ W1, const float* __restrict__ W2,
                      unsigned short* __restrict__ Wp1, unsigned short* __restrict__ Wp2,
                      int* __restrict__ btail) {
    int idx = blockIdx.x * 256 + threadIdx.x;   // 0..2047
    if (idx < 1024) {                           // W1: K=128 -> 4 chunks x 4 tiles
        int l = idx & 63, tc = idx >> 6;
        int c = tc & 3, t = tc >> 2;
        for (int j = 0; j < 8; ++j)
            Wp1[idx * 8 + j] = f2bf(W1[(c * 32 + (l >> 4) * 8 + j) * H_DIM + t * 16 + (l & 15)]);
    } else if (idx < 1536) {                    // W2: K=64 -> 2 chunks x 4 tiles
        int i2 = idx - 1024;
        int l = i2 & 63, tc = i2 >> 6;
        int c = tc & 1, t = tc >> 1;
        for (int j = 0; j < 8; ++j)
            Wp2[i2 * 8 + j] = f2bf(W2[(c * 32 + (l >> 4) * 8 + j) * H_DIM + t * 16 + (l & 15)]);
    } else if (idx - 1536 < NBKT) {
        int b = idx - 1536;
        btail[b] = b * BKT_CAP;
    }
}

// ---------------- CSR build (fixed-capacity buckets) ----------------

__global__ void bin_edges(const int* __restrict__ ei, int* __restrict__ btail,
                          unsigned int* __restrict__ bins) {
    __shared__ int hist[NBKT];
    __shared__ int base[NBKT];
    int tid = threadIdx.x;
    for (int b = tid; b < NBKT; b += 256) hist[b] = 0;
    __syncthreads();
    int e0 = blockIdx.x * BIN_CHUNK;
    unsigned short rank[BIN_T];
#pragma unroll
    for (int t = 0; t < BIN_T; ++t) {
        int e = e0 + t * 256 + tid;
        int r = 0;
        if (e < N_EDGES) {
            int b = ei[N_EDGES + e] >> 8;
            r = atomicAdd(&hist[b], 1);
        }
        rank[t] = (unsigned short)r;
    }
    __syncthreads();
    for (int b = tid; b < NBKT; b += 256) {
        int c = hist[b];
        base[b] = c ? atomicAdd(&btail[b], c) : 0;
    }
    __syncthreads();
#pragma unroll
    for (int t = 0; t < BIN_T; ++t) {
        int e = e0 + t * 256 + tid;
        if (e < N_EDGES) {
            int src = ei[e];
            int dst = ei[N_EDGES + e];
            int b = dst >> 8;
            int idx = base[b] + (int)rank[t];
            if (idx >= BINS_CAP) idx = BINS_CAP - 1;   // impossible-overflow guard
            bins[idx] = (unsigned int)src | ((unsigned int)(dst & 255) << 17);
        }
    }
}

// One block per bucket: per-node counts (LDS), block scan -> packed rowdeg
// (beg | deg<<22) + dinv, then dense in-bucket scatter into colsrc.
__global__ void bucket_build(const unsigned int* __restrict__ bins, const int* __restrict__ btail,
                             int* __restrict__ rowdeg, float* __restrict__ dinv,
                             int* __restrict__ colsrc) {
    __shared__ int cnt[256];
    __shared__ int pfx[256];
    __shared__ int cur[256];
    __shared__ int ws[4];
    int bkt  = blockIdx.x;
    int base = bkt << 8;
    int tid  = threadIdx.x;
    int nn   = N_NODES - base; if (nn > 256) nn = 256;
    int pbeg = bkt * BKT_CAP, pend = btail[bkt];

    cnt[tid] = 0; cur[tid] = 0;
    __syncthreads();
    for (int p = pbeg + tid; p < pend; p += 256)
        atomicAdd(&cnt[bins[p] >> 17], 1);
    __syncthreads();

    int lane = tid & 63, wid = tid >> 6;
    int v   = cnt[tid];
    int inc = v;
    for (int off = 1; off < 64; off <<= 1) {
        int u = __shfl_up(inc, off);
        if (lane >= off) inc += u;
    }
    if (lane == 63) ws[wid] = inc;
    __syncthreads();
    int woff = 0;
    for (int w = 0; w < wid; ++w) woff += ws[w];
    pfx[tid] = woff + inc - v;   // exclusive prefix within bucket
    __syncthreads();

    if (tid < nn) {
        rowdeg[base + tid] = (pbeg + pfx[tid]) | (v << 22);
        dinv[base + tid]   = rsqrtf((float)v + 1.0f);   // +1 self-loop
    }

    for (int p = pbeg + tid; p < pend; p += 256) {
        unsigned int pk = bins[p];
        int ld  = (int)(pk >> 17);
        int loc = atomicAdd(&cur[ld], 1);
        colsrc[pbeg + pfx[ld] + loc] = (int)(pk & 0x1FFFFu);
    }
}

// ---------------- MFMA GEMM:  Y[row][col] = (A[row][:] @ W[:,col]) * dinv[row] -> fp8 ------

template<int K, bool ABF>
__global__ void gemm_mfma(const void* __restrict__ Ap, const unsigned short* __restrict__ Wp,
                          const float* __restrict__ dinv, unsigned char* __restrict__ Y) {
    int lane = threadIdx.x & 63;
    int wave = threadIdx.x >> 6;
    int l16 = lane & 15, lhi = lane >> 4;
    int row0 = blockIdx.x * 64 + wave * 16;
    int arow = row0 + l16;
    bool aok = (arow < N_NODES);

    f32x4 acc[4];
#pragma unroll
    for (int t = 0; t < 4; ++t) acc[t] = (f32x4){0.f, 0.f, 0.f, 0.f};

#pragma unroll
    for (int c = 0; c < K / 32; ++c) {
        bf16x8 a;
        if (ABF) {
            if (aok) a = *(const bf16x8*)((const unsigned short*)Ap + (size_t)arow * K + c * 32 + lhi * 8);
            else     a = (bf16x8){0, 0, 0, 0, 0, 0, 0, 0};
        } else {
            if (aok) {
                const float* Af = (const float*)Ap + (size_t)arow * K + c * 32 + lhi * 8;
                float4 f0 = *(const float4*)(Af);
                float4 f1 = *(const float4*)(Af + 4);
                a = (bf16x8){(short)f2bf(f0.x), (short)f2bf(f0.y), (short)f2bf(f0.z), (short)f2bf(f0.w),
                             (short)f2bf(f1.x), (short)f2bf(f1.y), (short)f2bf(f1.z), (short)f2bf(f1.w)};
            } else a = (bf16x8){0, 0, 0, 0, 0, 0, 0, 0};
        }
#pragma unroll
        for (int t = 0; t < 4; ++t) {
            bf16x8 b = *(const bf16x8*)(Wp + ((size_t)(t * (K / 32) + c) * 64 + lane) * 8);
            acc[t] = __builtin_amdgcn_mfma_f32_16x16x32_bf16(a, b, acc[t], 0, 0, 0);
        }
    }

#pragma unroll
    for (int r = 0; r < 4; ++r) {
        int row = row0 + lhi * 4 + r;
        if (row < N_NODES) {
            float dv = dinv[row];
#pragma unroll
            for (int t = 0; t < 4; ++t)
                Y[(size_t)row * H_DIM + t * 16 + l16] = ftofp8(acc[t][r] * dv);
        }
    }
}

// ---------------- aggregation: 8 nodes/wave, 8 lanes/node, no LDS, no reduce --------------
// Lane group g (8 lanes) owns node base+g; lane f8 accumulates feature octet 8f8..8f8+7
// across ALL of its node's edges. Exec-masked loads: memory issued == E gathers exactly.
// out = [relu](dinv[i]*(sum_{e:dst=i} h'[src] + h'[i]) + b), h' fp8 pre-scaled; out bf16.

template<int RELU>
__global__ void __launch_bounds__(256, 8)
agg_fp8(const unsigned char* __restrict__ Hq, const float* __restrict__ dinv,
        const int* __restrict__ rowdeg, const int* __restrict__ colsrc,
        const float* __restrict__ bias, unsigned short* __restrict__ Z) {
    int tid  = threadIdx.x;
    int lane = tid & 63;
    int g    = lane >> 3;                 // node group 0..7
    int f8   = lane & 7;                  // feature octet
    int node = blockIdx.x * 32 + (tid >> 6) * 8 + g;   // 3125 blocks x 32 nodes (exact)

    const uint2* H = (const uint2*)Hq;

    f32x2 a01 = {0.f, 0.f}, a23 = {0.f, 0.f}, a45 = {0.f, 0.f}, a67 = {0.f, 0.f};
    auto acc8 = [&](uint2 gg) {
        a01 += __builtin_amdgcn_cvt_pk_f32_fp8((int)gg.x, false);
        a23 += __builtin_amdgcn_cvt_pk_f32_fp8((int)gg.x, true);
        a45 += __builtin_amdgcn_cvt_pk_f32_fp8((int)gg.y, false);
        a67 += __builtin_amdgcn_cvt_pk_f32_fp8((int)gg.y, true);
    };

    acc8(H[(size_t)node * 8 + f8]);       // self term (coalesced across groups)

    int rd  = rowdeg[node];
    int p   = rd & 0x3FFFFF;
    int end = p + (int)((unsigned)rd >> 22);

    while (__any(p < end)) {
        bool v0 = p < end;
        bool v1 = p + 1 < end;
        int s0 = v0 ? colsrc[p]     : 0;  // exec-masked loads
        int s1 = v1 ? colsrc[p + 1] : 0;
        if (v0) {
            uint2 g0 = H[(size_t)s0 * 8 + f8];
            acc8(g0);
        }
        if (v1) {
            uint2 g1 = H[(size_t)s1 * 8 + f8];
            acc8(g1);
        }
        p += 2;
    }

    float dv = dinv[node];
    float4 b0 = *(const float4*)(bias + 8 * f8);
    float4 b1 = *(const float4*)(bias + 8 * f8 + 4);
    float v0 = a01.x * dv + b0.x, v1 = a01.y * dv + b0.y;
    float v2 = a23.x * dv + b0.z, v3 = a23.y * dv + b0.w;
    float v4 = a45.x * dv + b1.x, v5 = a45.y * dv + b1.y;
    float v6 = a67.x * dv + b1.z, v7 = a67.y * dv + b1.w;
    if (RELU) {
        v0 = fmaxf(v0, 0.f); v1 = fmaxf(v1, 0.f); v2 = fmaxf(v2, 0.f); v3 = fmaxf(v3, 0.f);
        v4 = fmaxf(v4, 0.f); v5 = fmaxf(v5, 0.f); v6 = fmaxf(v6, 0.f); v7 = fmaxf(v7, 0.f);
    }
    uint4 pk;
    pk.x = (unsigned int)f2bf(v0) | ((unsigned int)f2bf(v1) << 16);
    pk.y = (unsigned int)f2bf(v2) | ((unsigned int)f2bf(v3) << 16);
    pk.z = (unsigned int)f2bf(v4) | ((unsigned int)f2bf(v5) << 16);
    pk.w = (unsigned int)f2bf(v6) | ((unsigned int)f2bf(v7) << 16);
    *(((uint4*)Z) + (size_t)node * 8 + f8) = pk;
}

// ---------------- fused pooling + head (batch sorted -> contiguous segments) ----------------

__global__ void pool_head(const unsigned short* __restrict__ Hb, const int* __restrict__ batch,
                          const float* __restrict__ Wl, const float* __restrict__ bl,
                          float* __restrict__ out) {
    int g   = blockIdx.x;
    int tid = threadIdx.x;   // 0..255

    auto lb = [&](int key) {
        int lo = 0, hi = N_NODES;
        while (lo < hi) {
            int mid = (lo + hi) >> 1;
            if (batch[mid] < key) lo = mid + 1; else hi = mid;
        }
        return lo;
    };
    int beg = lb(g);
    int end = lb(g + 1);

    int fq = tid & 15;       // feature quad (features 4fq..4fq+3)
    int rg = tid >> 4;       // 16 row groups
    const uint2* H = (const uint2*)Hb;
    float4 acc = {0.f, 0.f, 0.f, 0.f};
    for (int i = beg + rg; i < end; i += 16) {
        uint2 gg = H[(size_t)i * 16 + fq];
        acc.x += bflo(gg.x); acc.y += bfhi(gg.x);
        acc.z += bflo(gg.y); acc.w += bfhi(gg.y);
    }

    __shared__ float4 s[16][16];
    __shared__ float  pl[64];
    s[rg][fq] = acc;
    __syncthreads();

    if (tid < 16) {
        float4 t = s[0][tid];
        for (int r = 1; r < 16; ++r) {
            t.x += s[r][tid].x; t.y += s[r][tid].y;
            t.z += s[r][tid].z; t.w += s[r][tid].w;
        }
        float inv = 1.0f / fmaxf((float)(end - beg), 1.0f);
        pl[4 * tid]     = t.x * inv;
        pl[4 * tid + 1] = t.y * inv;
        pl[4 * tid + 2] = t.z * inv;
        pl[4 * tid + 3] = t.w * inv;
    }
    __syncthreads();

    if (tid < 64) {
        float p = pl[tid];
        __shared__ float logits[N_CLS];
        for (int c = 0; c < N_CLS; ++c) {
            float v = p * Wl[tid * N_CLS + c];
            for (int off = 32; off; off >>= 1) v += __shfl_xor(v, off);
            if (tid == 0) logits[c] = v + bl[c];
        }
        if (tid == 0) {
            float m = logits[0];
            for (int c = 1; c < N_CLS; ++c) m = fmaxf(m, logits[c]);
            float sum = 0.f;
            for (int c = 0; c < N_CLS; ++c) sum += expf(logits[c] - m);
            float ls = logf(sum);
            for (int c = 0; c < N_CLS; ++c) out[g * N_CLS + c] = logits[c] - m - ls;
        }
    }
}

// ---------------- launch ----------------

extern "C" void kernel_launch(void* const* d_in, const int* in_sizes, int n_in,
                              void* d_out, int out_size, void* d_ws, size_t ws_size,
                              hipStream_t stream) {
    const float* x     = (const float*)d_in[0];
    const int*   ei    = (const int*)d_in[1];
    const int*   batch = (const int*)d_in[2];
    const float* W1    = (const float*)d_in[3];
    const float* b1    = (const float*)d_in[4];
    const float* W2    = (const float*)d_in[5];
    const float* b2    = (const float*)d_in[6];
    const float* Wl    = (const float*)d_in[7];
    const float* bl    = (const float*)d_in[8];
    float*       out   = (float*)d_out;

    char* p = (char*)d_ws;
    auto alloc = [&](size_t bytes) {
        char* r = p;
        p += (bytes + 255) & ~(size_t)255;
        return r;
    };
    int*            btail  = (int*)            alloc((size_t)NBKT * 4);
    int*            rowdeg = (int*)            alloc((size_t)N_NODES * 4);
    float*          dinv   = (float*)          alloc((size_t)N_NODES * 4);
    int*            colsrc = (int*)            alloc((size_t)BINS_CAP * 4);
    unsigned int*   bins   = (unsigned int*)   alloc((size_t)BINS_CAP * 4);
    unsigned char*  hA8    = (unsigned char*)  alloc((size_t)N_NODES * H_DIM);
    unsigned short* hB     = (unsigned short*) alloc((size_t)N_NODES * H_DIM * 2);
    unsigned short* Wp1    = (unsigned short*) alloc((size_t)1024 * 8 * 2);
    unsigned short* Wp2    = (unsigned short*) alloc((size_t)512 * 8 * 2);

    int agg_nb = N_NODES / 32;     // 3125 (exact)
    int gb     = (N_NODES + 63) / 64;

    setup       <<<8, 256, 0, stream>>>(W1, W2, Wp1, Wp2, btail);
    bin_edges   <<<BIN_NB, 256, 0, stream>>>(ei, btail, bins);
    bucket_build<<<NBKT, 256, 0, stream>>>(bins, btail, rowdeg, dinv, colsrc);

    gemm_mfma<F_IN, false><<<gb, 256, 0, stream>>>(x, Wp1, dinv, hA8);          // h1' fp8
    agg_fp8<1><<<agg_nb, 256, 0, stream>>>(hA8, dinv, rowdeg, colsrc, b1, hB);  // z1 bf16
    gemm_mfma<H_DIM, true><<<gb, 256, 0, stream>>>(hB, Wp2, dinv, hA8);         // h2' fp8
    agg_fp8<0><<<agg_nb, 256, 0, stream>>>(hA8, dinv, rowdeg, colsrc, b2, hB);  // z2 bf16
    pool_head<<<N_GRAPH, 256, 0, stream>>>(hB, batch, Wl, bl, out);
}